// Round 17
// baseline (216.599 us; speedup 1.0000x reference)
//
#include <hip/hip_runtime.h>
#include <hip/hip_bf16.h>
#include <stdint.h>

typedef unsigned short u16;
typedef __attribute__((ext_vector_type(4))) float f32x4;
typedef __attribute__((ext_vector_type(16))) float f32x16;
typedef __attribute__((ext_vector_type(8))) __bf16 bf16x8;

#define NB 2
#define NT 2048
#define NC 2048
#define NH 16
#define NKV 4
#define HD 128
#define NQKV 3072
#define SCALE2 0.12751739f  // (1/sqrt(128)) * log2(e)

__device__ __forceinline__ u16 f2bf(float f) {
  union { float f; uint32_t u; } c; c.f = f;
  uint32_t u = c.u + 0x7fffu + ((c.u >> 16) & 1u);
  return (u16)(u >> 16);
}
__device__ __forceinline__ float bf2f(u16 h) {
  union { uint32_t u; float f; } c; c.u = ((uint32_t)h) << 16;
  return c.f;
}
__device__ __forceinline__ uint32_t packbf2(float a, float b) {
  return (uint32_t)f2bf(a) | ((uint32_t)f2bf(b) << 16);
}

// global -> LDS async copy, 16B per lane. LDS dest = wave-uniform base + lane*16.
__device__ __forceinline__ void gload16(const void* g, void* lds) {
  __builtin_amdgcn_global_load_lds(
      (__attribute__((address_space(1))) void*)(uintptr_t)g,
      (__attribute__((address_space(3))) void*)(uint32_t)(uintptr_t)lds,
      16, 0, 0);
}

// ---------------- fp32 -> bf16 convert ----------------
__global__ void cvt_bf16_kernel(const float* __restrict__ in, u16* __restrict__ out, int n4) {
  int i = blockIdx.x * blockDim.x + threadIdx.x;
  if (i >= n4) return;
  float4 v = ((const float4*)in)[i];
  uint32_t lo = (uint32_t)f2bf(v.x) | ((uint32_t)f2bf(v.y) << 16);
  uint32_t hi = (uint32_t)f2bf(v.z) | ((uint32_t)f2bf(v.w) << 16);
  ((uint2*)out)[i] = make_uint2(lo, hi);
}

// ---------------- RoPE cos/sin table ----------------
__global__ void rope_tab_kernel(float* __restrict__ tab) {
  int idx = blockIdx.x * blockDim.x + threadIdx.x;  // NT*64
  int t = idx >> 6, i = idx & 63;
  float inv = expf(-(float)(2 * i) * (9.210340371976184f / 128.f));
  float f = (float)t * inv;
  tab[t * 128 + i] = cosf(f);
  tab[t * 128 + 64 + i] = sinf(f);
}

// ---------------- RoPE apply + head split/transpose (Q and K only) ----------------
__global__ void rope_apply_kernel(const u16* __restrict__ qkv, const float* __restrict__ tab,
                                  u16* __restrict__ Q, u16* __restrict__ K) {
  int idx = blockIdx.x * blockDim.x + threadIdx.x;  // NB*NT*20*64
  int i = idx & 63;
  int rest = idx >> 6;
  int hh = rest % 20;
  int bt = rest / 20;
  int t = bt & (NT - 1);
  int b = bt >> 11;
  const u16* src_row = qkv + (long)bt * NQKV;
  float c = tab[t * 128 + i], s = tab[t * 128 + 64 + i];
  if (hh < NH) {
    const u16* sp = src_row + hh * HD;
    float x0 = bf2f(sp[i]), x1 = bf2f(sp[i + 64]);
    u16* dp = Q + ((long)(b * NH + hh) * NT + t) * HD;
    dp[i] = f2bf((x0 * c - x1 * s) * SCALE2);
    dp[i + 64] = f2bf((x1 * c + x0 * s) * SCALE2);
  } else {
    int kh = hh - NH;
    const u16* sp = src_row + (NH + kh) * HD;
    float x0 = bf2f(sp[i]), x1 = bf2f(sp[i + 64]);
    u16* dp = K + ((long)(b * NKV + kh) * NT + t) * HD;
    dp[i] = f2bf(x0 * c - x1 * s);
    dp[i + 64] = f2bf(x1 * c + x0 * s);
  }
}

// ---------------- V transpose to attn-ready layout ----------------
// Output Vt2[bkh][drow=d>>1][tile=t>>6][(d&1)*64 + pos] with pos = 16*(t'>>4) + sigma(t'&15)
// (t' = t&63), sigma = quad-swap (self-inverse), via swapping pk[2,3]<->pk[4,5].
__global__ void vtrans_kernel(const u16* __restrict__ qkv, u16* __restrict__ Vt) {
  __shared__ u16 tile[64][72];
  const int t0 = (blockIdx.x >> 1) * 64;
  const int d0 = (blockIdx.x & 1) * 64;
  const int bkh = blockIdx.y;                 // b*NKV + kh
  const int tid = threadIdx.x;
  const int tr = tid >> 2;
  const int tc = (tid & 3) * 16;
  const u16* src = qkv + ((long)((bkh >> 2) * NT) + t0 + tr) * NQKV +
                   (NH + NKV) * HD + (bkh & 3) * HD + d0 + tc;
  uint4 v0 = *(const uint4*)(src);
  uint4 v1 = *(const uint4*)(src + 8);
  *(uint4*)&tile[tr][tc] = v0;
  *(uint4*)&tile[tr][tc + 8] = v1;
  __syncthreads();
  const int dr = tid >> 2;
  const int tcc = (tid & 3) * 16;
  uint32_t pk[8];
#pragma unroll
  for (int e = 0; e < 8; ++e) {
    u16 a = tile[tcc + 2 * e][dr];
    u16 bq = tile[tcc + 2 * e + 1][dr];
    pk[e] = (uint32_t)a | ((uint32_t)bq << 16);
  }
  uint32_t tmp;
  tmp = pk[2]; pk[2] = pk[4]; pk[4] = tmp;
  tmp = pk[3]; pk[3] = pk[5]; pk[5] = tmp;
  const int d = d0 + dr;
  const int t = t0 + tcc;
  u16* dst = Vt + (long)bkh * HD * NT + (long)(d >> 1) * (2 * NT) +
             (t >> 6) * 128 + (d & 1) * 64 + (t & 48);
  *(uint4*)(dst) = *(uint4*)&pk[0];
  *(uint4*)(dst + 8) = *(uint4*)&pk[4];
}

// ---------------- GEMM v3: BM=256 x BN=(NREP*32), BK=64, counted-vmcnt pipeline ----------------
template <int OUT_BF16, int NREP>
__global__ __launch_bounds__(512, 1) void gemm256_kernel(const u16* __restrict__ A,
                                                         const u16* __restrict__ Bm,
                                                         void* __restrict__ Cm,
                                                         int M, int N, int K) {
  constexpr int BN = NREP * 32;
  __shared__ __align__(16) u16 As[2][256 * 64];   // 32 KB per buf
  __shared__ __align__(16) u16 Bs[2][BN * 64];    // 16 or 24 KB per buf
  const int tid = threadIdx.x, lane = tid & 63, wid = tid >> 6;
  const int wr = wid >> 1, wc = wid & 1;
  const int g = lane >> 4, r = lane & 15;
  const long row0 = (long)blockIdx.y * 256;
  const long col0 = (long)blockIdx.x * BN;
  const int lrow = lane >> 3;
  const int lch = lane & 7;

  f32x4 acc[4][NREP] = {};

  auto stage = [&](int bufi, int kt) {
    const int k0 = kt * 64;
    u16* Ad = As[bufi];
    u16* Bd = Bs[bufi];
#pragma unroll
    for (int ii = 0; ii < 4; ++ii) {
      int rowl = wid * 32 + ii * 8 + lrow;
      const u16* src = A + (row0 + rowl) * (long)K + k0 + ((lch ^ (rowl & 7)) * 8);
      gload16(src, Ad + (wid * 32 + ii * 8) * 64);
    }
#pragma unroll
    for (int ii = 0; ii < NREP / 2; ++ii) {
      int rowl = wid * (NREP * 4) + ii * 8 + lrow;
      const u16* src = Bm + (col0 + rowl) * (long)K + k0 + ((lch ^ (rowl & 7)) * 8);
      gload16(src, Bd + (wid * (NREP * 4) + ii * 8) * 64);
    }
  };

  const int nt = K / 64;
  stage(0, 0);
  int buf = 0;
  for (int t = 0; t < nt; ++t) {
    if (t + 1 < nt) {
      stage(buf ^ 1, t + 1);
      __builtin_amdgcn_sched_barrier(0);
      if constexpr (NREP == 4) {
        asm volatile("s_waitcnt vmcnt(6)" ::: "memory");
      } else {
        asm volatile("s_waitcnt vmcnt(7)" ::: "memory");
      }
    } else {
      __builtin_amdgcn_sched_barrier(0);
      asm volatile("s_waitcnt vmcnt(0)" ::: "memory");
    }
    __builtin_amdgcn_sched_barrier(0);
    __builtin_amdgcn_s_barrier();
    __builtin_amdgcn_sched_barrier(0);

    const char* Ab = (const char*)As[buf];
    const char* Bb = (const char*)Bs[buf];
#pragma unroll
    for (int ks = 0; ks < 2; ++ks) {
      bf16x8 af[4], bfv[NREP];
#pragma unroll
      for (int mi = 0; mi < 4; ++mi) {
        int row = wr * 64 + mi * 16 + r;
        af[mi] = *(const bf16x8*)(Ab + row * 128 + (((4 * ks + g) ^ (row & 7)) * 16));
      }
#pragma unroll
      for (int ni = 0; ni < NREP; ++ni) {
        int row = wc * (NREP * 16) + ni * 16 + r;
        bfv[ni] = *(const bf16x8*)(Bb + row * 128 + (((4 * ks + g) ^ (row & 7)) * 16));
      }
      __builtin_amdgcn_s_setprio(1);
#pragma unroll
      for (int mi = 0; mi < 4; ++mi)
#pragma unroll
        for (int ni = 0; ni < NREP; ++ni)
          acc[mi][ni] = __builtin_amdgcn_mfma_f32_16x16x32_bf16(af[mi], bfv[ni], acc[mi][ni], 0, 0, 0);
      __builtin_amdgcn_s_setprio(0);
    }
    __builtin_amdgcn_sched_barrier(0);
    __builtin_amdgcn_s_barrier();
    __builtin_amdgcn_sched_barrier(0);
    buf ^= 1;
  }

#pragma unroll
  for (int mi = 0; mi < 4; ++mi)
#pragma unroll
    for (int ni = 0; ni < NREP; ++ni)
#pragma unroll
      for (int j = 0; j < 4; ++j) {
        long rr = row0 + wr * 64 + mi * 16 + g * 4 + j;
        long cc = col0 + wc * (NREP * 16) + ni * 16 + r;
        float v = acc[mi][ni][j];
        if (OUT_BF16) ((u16*)Cm)[rr * N + cc] = f2bf(v);
        else          ((float*)Cm)[rr * N + cc] = v;
      }
}

// ---------------- Flash attention v11: split-KV for long q-tiles ----------------
// split_en=0: 512 blocks, (id,id+256) complementary pairs, all write Y (round-15 path).
// split_en=1: 768 blocks. ids 0..255: qt 0..7 full-range, write Y. ids 256..767:
// qt 8..15 split in two KV halves (<=16 iters each) writing bf16 O-partials + (m,l).
__global__ __launch_bounds__(256, 2) void attn_kernel(const u16* __restrict__ Qg,
                                                      const u16* __restrict__ Kg,
                                                      const u16* __restrict__ Vtg,
                                                      const float* __restrict__ amask,
                                                      u16* __restrict__ Y,
                                                      u16* __restrict__ Op,
                                                      float* __restrict__ Lm,
                                                      int split_en) {
  __shared__ __align__(16) u16 Ks[2][64 * 128];
  __shared__ __align__(16) u16 Vs[2][64 * 128];
  const int tid = threadIdx.x, lane = tid & 63, wid = tid >> 6;
  const int ql = lane & 31, hi = lane >> 5;
  const int id = blockIdx.x;
  int h, qt, b, kvlo, kvhi, part;
  if (!split_en) {
    h = id & 15;
    int xp = (id >> 4) & 7;
    b = (id >> 7) & 1;
    qt = (id >> 8) ? 15 - xp : xp;
    kvlo = 0; kvhi = 2 * qt + 2; part = -1;
  } else if (id < 256) {
    h = id & 15; qt = (id >> 4) & 7; b = id >> 7;
    kvlo = 0; kvhi = 2 * qt + 2; part = -1;
  } else {
    int j = id - 256;
    part = j >> 8;
    int k = j & 255;
    h = k & 15; qt = 8 + ((k >> 4) & 7); b = k >> 7;
    int n = 2 * qt + 2, n0 = qt + 1;
    kvlo = part ? n0 : 0;
    kvhi = part ? n : n0;
  }
  const int q0 = qt * 128;
  const int kh = h >> 2;

  const u16* Kbh = Kg + (long)(b * NKV + kh) * NT * HD;
  const u16* Vtbh = Vtg + (long)(b * NKV + kh) * HD * NT;
  const u16* Qbh = Qg + (long)(b * NH + h) * NT * HD;
  const float* am_b = amask + b * NT;

  const int srow = lane >> 4;
  const int schunk = lane & 15;
  auto stageK = [&](u16* dst, int kv0) {
#pragma unroll
    for (int ii = 0; ii < 4; ++ii) {
      int kvl = wid * 16 + ii * 4 + srow;
      const u16* src = Kbh + (long)(kv0 + kvl) * HD + ((schunk ^ (kvl & 15)) * 8);
      gload16(src, dst + (wid * 16 + ii * 4) * 128);
    }
  };
  auto stageV = [&](u16* dst, int kv0) {
    const u16* vb = Vtbh + (kv0 >> 6) * 128;
#pragma unroll
    for (int ii = 0; ii < 4; ++ii) {
      int R = wid * 16 + ii * 4 + srow;
      const u16* src = vb + (long)R * (2 * NT) + ((schunk ^ (R & 15)) * 8);
      gload16(src, dst + (wid * 16 + ii * 4) * 128);
    }
  };

  bf16x8 qf[8];
  {
    const u16* Qrow = Qbh + (long)(q0 + wid * 32 + ql) * HD;
#pragma unroll
    for (int ks = 0; ks < 8; ++ks)
      qf[ks] = *(const bf16x8*)(Qrow + ks * 16 + 8 * hi);
  }

  // ---- prologue ----
  stageK(Ks[0], kvlo * 64);
  stageV(Vs[0], kvlo * 64);
  __syncthreads();

  float m = -INFINITY;
  f32x4 lacc = {};
  f32x16 o[4] = {};
  int buf = 0;
  const int qi = q0 + wid * 32 + ql;

  for (int i = kvlo; i < kvhi; ++i) {
    const int kv0 = i * 64;

    if (i + 1 < kvhi) {
      stageK(Ks[buf ^ 1], (i + 1) * 64);
      stageV(Vs[buf ^ 1], (i + 1) * 64);
    }

    const char* Ksb = (const char*)Ks[buf];
    const char* Vsb = (const char*)Vs[buf];

    // ---- S^T = mfma(K, Q): 4 independent chains of 4 (split accumulators) ----
    f32x16 s0a = {}, s0b = {}, s1a = {}, s1b = {};
    __builtin_amdgcn_s_setprio(1);
#pragma unroll
    for (int ks = 0; ks < 4; ++ks) {
      bf16x8 kf0 = *(const bf16x8*)(Ksb + ql * 256 + (((2 * ks + hi) ^ (ql & 15)) * 16));
      bf16x8 kf1 = *(const bf16x8*)(Ksb + (32 + ql) * 256 + (((2 * ks + hi) ^ (ql & 15)) * 16));
      s0a = __builtin_amdgcn_mfma_f32_32x32x16_bf16(kf0, qf[ks], s0a, 0, 0, 0);
      s1a = __builtin_amdgcn_mfma_f32_32x32x16_bf16(kf1, qf[ks], s1a, 0, 0, 0);
    }
#pragma unroll
    for (int ks = 4; ks < 8; ++ks) {
      bf16x8 kf0 = *(const bf16x8*)(Ksb + ql * 256 + (((2 * ks + hi) ^ (ql & 15)) * 16));
      bf16x8 kf1 = *(const bf16x8*)(Ksb + (32 + ql) * 256 + (((2 * ks + hi) ^ (ql & 15)) * 16));
      s0b = __builtin_amdgcn_mfma_f32_32x32x16_bf16(kf0, qf[ks], s0b, 0, 0, 0);
      s1b = __builtin_amdgcn_mfma_f32_32x32x16_bf16(kf1, qf[ks], s1b, 0, 0, 0);
    }
    __builtin_amdgcn_s_setprio(0);
    f32x16 s0 = s0a + s0b;
    f32x16 s1 = s1a + s1b;

    // ---- causal mask (tiles overlapping the diagonal zone) ----
    if (i >= 2 * qt) {
#pragma unroll
      for (int reg = 0; reg < 16; ++reg) {
        int kvl = (reg & 3) + 8 * (reg >> 2) + 4 * hi;
        if (kv0 + kvl > qi) s0[reg] = -INFINITY;
        if (kv0 + 32 + kvl > qi) s1[reg] = -INFINITY;
      }
    }

    // ---- defer-max: binary tree, wave-uniform check ----
    float t16[16];
#pragma unroll
    for (int reg = 0; reg < 16; ++reg) t16[reg] = fmaxf(s0[reg], s1[reg]);
    float t8[8];
#pragma unroll
    for (int reg = 0; reg < 8; ++reg) t8[reg] = fmaxf(t16[reg], t16[reg + 8]);
    float t4[4];
#pragma unroll
    for (int reg = 0; reg < 4; ++reg) t4[reg] = fmaxf(t8[reg], t8[reg + 4]);
    float mxl = fmaxf(fmaxf(t4[0], t4[1]), fmaxf(t4[2], t4[3]));
    if (!__all(mxl <= m + 8.f)) {
      float mx = fmaxf(mxl, __shfl_xor(mxl, 32));
      float mnew = fmaxf(m, mx);
      float alpha = exp2f(m - mnew);
      m = mnew;
      lacc *= alpha;
#pragma unroll
      for (int dblk = 0; dblk < 4; ++dblk) o[dblk] *= alpha;
    }

    // ---- P = exp2(S - m) * mask ----
    float4 am0[4], am1[4];
#pragma unroll
    for (int uu = 0; uu < 4; ++uu) {
      am0[uu] = *(const float4*)(am_b + kv0 + 8 * uu + 4 * hi);
      am1[uu] = *(const float4*)(am_b + kv0 + 32 + 8 * uu + 4 * hi);
    }
#pragma unroll
    for (int reg = 0; reg < 16; ++reg) {
      float p0 = exp2f(s0[reg] - m) * (&am0[reg >> 2].x)[reg & 3];
      float p1 = exp2f(s1[reg] - m) * (&am1[reg >> 2].x)[reg & 3];
      s0[reg] = p0; s1[reg] = p1;
      lacc[reg & 3] += p0 + p1;
    }

    // ---- pack P fragments from own regs (sigma-matched, no LDS) ----
    bf16x8 pb[4];
#pragma unroll
    for (int ks = 0; ks < 4; ++ks) {
      union { __bf16 hh[8]; bf16x8 v; } pk;
      const int base = 8 * (ks & 1);
#pragma unroll
      for (int j = 0; j < 8; ++j)
        pk.hh[j] = (__bf16)((ks >= 2) ? s1[base + j] : s0[base + j]);
      pb[ks] = pk.v;
    }

    // ---- O^T += mfma(V^T, P): 4 independent chains ----
    __builtin_amdgcn_s_setprio(1);
#pragma unroll
    for (int ks = 0; ks < 4; ++ks) {
#pragma unroll
      for (int dblk = 0; dblk < 4; ++dblk) {
        int drow = dblk * 16 + (ql >> 1);
        int gr = ((ql & 1) * 8 + 2 * ks + hi) ^ (drow & 15);
        bf16x8 va = *(const bf16x8*)(Vsb + drow * 256 + gr * 16);
        o[dblk] = __builtin_amdgcn_mfma_f32_32x32x16_bf16(va, pb[ks], o[dblk], 0, 0, 0);
      }
    }
    __builtin_amdgcn_s_setprio(0);

    __syncthreads();
    buf ^= 1;
  }

  // ---- epilogue ----
  {
    float l = (lacc[0] + lacc[1]) + (lacc[2] + lacc[3]);
    l += __shfl_xor(l, 32);
    if (part < 0) {
      float invl = 1.f / l;
      u16* Yrow = Y + ((long)b * NT + qi) * NC + h * HD;
#pragma unroll
      for (int dblk = 0; dblk < 4; ++dblk)
#pragma unroll
        for (int uu = 0; uu < 4; ++uu) {
          int d = dblk * 32 + 8 * uu + 4 * hi;
          int r0 = 4 * uu;
          *(uint2*)(Yrow + d) = make_uint2(
              packbf2(o[dblk][r0] * invl, o[dblk][r0 + 1] * invl),
              packbf2(o[dblk][r0 + 2] * invl, o[dblk][r0 + 3] * invl));
        }
    } else {
      const int inst = ((b * 16 + h) << 3) + (qt - 8);   // b*128 + h*8 + qtm8
      const long rbase = (long)(part * 256 + inst) * 128 + wid * 32 + ql;
      u16* Orow = Op + rbase * 128;
#pragma unroll
      for (int dblk = 0; dblk < 4; ++dblk)
#pragma unroll
        for (int uu = 0; uu < 4; ++uu) {
          int d = dblk * 32 + 8 * uu + 4 * hi;
          int r0 = 4 * uu;
          *(uint2*)(Orow + d) = make_uint2(
              packbf2(o[dblk][r0], o[dblk][r0 + 1]),
              packbf2(o[dblk][r0 + 2], o[dblk][r0 + 3]));
        }
      if (hi == 0) *(float2*)(Lm + rbase * 2) = make_float2(m, l);
    }
  }
}

// ---------------- combine partials: Y = (a0*O0 + a1*O1) / (a0*l0 + a1*l1) ----------------
__global__ __launch_bounds__(256) void attn_combine_kernel(const u16* __restrict__ Op,
                                                           const float* __restrict__ Lm,
                                                           u16* __restrict__ Y) {
  const int k = blockIdx.x, tid = threadIdx.x;
  // decode matches attn's inst packing: k = b*128 + h*8 + qtm8
  const int b = k >> 7, h = (k >> 3) & 15, qtm8 = k & 7;
  const int row = tid >> 1, dbase = (tid & 1) * 64;
  const long r0 = (long)k * 128 + row;
  const long r1 = (long)(256 + k) * 128 + row;
  float2 ml0 = *(const float2*)(Lm + r0 * 2);
  float2 ml1 = *(const float2*)(Lm + r1 * 2);
  float M = fmaxf(ml0.x, ml1.x);
  float a0 = exp2f(ml0.x - M), a1 = exp2f(ml1.x - M);
  float invl = 1.f / (a0 * ml0.y + a1 * ml1.y);
  a0 *= invl; a1 *= invl;
  const u16* p0 = Op + r0 * 128 + dbase;
  const u16* p1 = Op + r1 * 128 + dbase;
  u16* Yrow = Y + ((long)b * NT + (qtm8 + 8) * 128 + row) * NC + h * HD + dbase;
#pragma unroll
  for (int e = 0; e < 8; ++e) {
    union { uint4 u; u16 hh[8]; } A, B2, O2;
    A.u = *(const uint4*)(p0 + e * 8);
    B2.u = *(const uint4*)(p1 + e * 8);
#pragma unroll
    for (int j = 0; j < 8; ++j)
      O2.hh[j] = f2bf(a0 * bf2f(A.hh[j]) + a1 * bf2f(B2.hh[j]));
    *(uint4*)(Yrow + e * 8) = O2.u;
  }
}

extern "C" void kernel_launch(void* const* d_in, const int* in_sizes, int n_in,
                              void* d_out, int out_size, void* d_ws, size_t ws_size,
                              hipStream_t stream) {
  const float* x = (const float*)d_in[0];
  const float* amask = (const float*)d_in[1];
  const float* w_qkv = (const float*)d_in[2];
  const float* w_proj = (const float*)d_in[3];

  const long MT = (long)NB * NT;  // 4096
  char* ws = (char*)d_ws;
  size_t off = 0;
  auto carve = [&](size_t bytes) -> char* {
    char* p = ws + off;
    off += (bytes + 255) & ~(size_t)255;
    return p;
  };
  u16* xb   = (u16*)carve((size_t)MT * NC * 2);       // A for gemm1; later Q
  u16* wqb  = (u16*)carve((size_t)NQKV * NC * 2);     // B for gemm1; later K + Vt
  u16* wpb  = (u16*)carve((size_t)NC * NC * 2);       // B for gemm2
  u16* qkvb = (u16*)carve((size_t)MT * NQKV * 2);     // C of gemm1; later Y
  float* tab = (float*)carve((size_t)NT * 128 * 4);
  u16* Op   = (u16*)carve((size_t)2 * 256 * 128 * 128 * 2);   // 16.8 MB bf16 O-partials
  float* Lm = (float*)carve((size_t)2 * 256 * 128 * 2 * 4);   // (m,l) partials
  const bool use_split = (off <= ws_size);

  u16* Qb = xb;
  u16* Kb = wqb;
  u16* Vtb = wqb + (size_t)NB * NKV * NT * HD;
  u16* Yb = qkvb;

  {
    int n4 = (int)(MT * NC / 4);
    cvt_bf16_kernel<<<dim3((n4 + 255) / 256), dim3(256), 0, stream>>>(x, xb, n4);
    n4 = (int)((long)NQKV * NC / 4);
    cvt_bf16_kernel<<<dim3((n4 + 255) / 256), dim3(256), 0, stream>>>(w_qkv, wqb, n4);
    n4 = (int)((long)NC * NC / 4);
    cvt_bf16_kernel<<<dim3((n4 + 255) / 256), dim3(256), 0, stream>>>(w_proj, wpb, n4);
  }
  rope_tab_kernel<<<dim3(NT * 64 / 256), dim3(256), 0, stream>>>(tab);
  gemm256_kernel<1, 6><<<dim3(NQKV / 192, MT / 256), dim3(512), 0, stream>>>(xb, wqb, qkvb, (int)MT, NQKV, NC);
  rope_apply_kernel<<<dim3(NB * NT * 20 * 64 / 256), dim3(256), 0, stream>>>(qkvb, tab, Qb, Kb);
  vtrans_kernel<<<dim3(NT / 64 * 2, NB * NKV), dim3(256), 0, stream>>>(qkvb, Vtb);
  if (use_split) {
    attn_kernel<<<dim3(768), dim3(256), 0, stream>>>(Qb, Kb, Vtb, amask, Yb, Op, Lm, 1);
    attn_combine_kernel<<<dim3(256), dim3(256), 0, stream>>>(Op, Lm, Yb);
  } else {
    attn_kernel<<<dim3(512), dim3(256), 0, stream>>>(Qb, Kb, Vtb, amask, Yb, Op, Lm, 0);
  }
  gemm256_kernel<0, 4><<<dim3(NC / 128, MT / 256), dim3(512), 0, stream>>>(Yb, wpb, d_out, (int)MT, NC, NC);
}

// Round 18
// 198.954 us; speedup vs baseline: 1.0887x; 1.0887x over previous
//
#include <hip/hip_runtime.h>
#include <hip/hip_bf16.h>
#include <stdint.h>

typedef unsigned short u16;
typedef __attribute__((ext_vector_type(4))) float f32x4;
typedef __attribute__((ext_vector_type(16))) float f32x16;
typedef __attribute__((ext_vector_type(8))) __bf16 bf16x8;

#define NB 2
#define NT 2048
#define NC 2048
#define NH 16
#define NKV 4
#define HD 128
#define NQKV 3072
#define SCALE2 0.12751739f  // (1/sqrt(128)) * log2(e)

__device__ __forceinline__ u16 f2bf(float f) {
  union { float f; uint32_t u; } c; c.f = f;
  uint32_t u = c.u + 0x7fffu + ((c.u >> 16) & 1u);
  return (u16)(u >> 16);
}
__device__ __forceinline__ float bf2f(u16 h) {
  union { uint32_t u; float f; } c; c.u = ((uint32_t)h) << 16;
  return c.f;
}
__device__ __forceinline__ uint32_t packbf2(float a, float b) {
  return (uint32_t)f2bf(a) | ((uint32_t)f2bf(b) << 16);
}

// global -> LDS async copy, 16B per lane. LDS dest = wave-uniform base + lane*16.
__device__ __forceinline__ void gload16(const void* g, void* lds) {
  __builtin_amdgcn_global_load_lds(
      (__attribute__((address_space(1))) void*)(uintptr_t)g,
      (__attribute__((address_space(3))) void*)(uint32_t)(uintptr_t)lds,
      16, 0, 0);
}

// ---------------- fp32 -> bf16 convert, grid-stride (single launch for all 3 tensors) ----------------
__global__ void cvt_bf16_kernel(const float* __restrict__ in, u16* __restrict__ out, int n4) {
  int stride = gridDim.x * blockDim.x;
  for (int i = blockIdx.x * blockDim.x + threadIdx.x; i < n4; i += stride) {
    float4 v = ((const float4*)in)[i];
    uint32_t lo = (uint32_t)f2bf(v.x) | ((uint32_t)f2bf(v.y) << 16);
    uint32_t hi = (uint32_t)f2bf(v.z) | ((uint32_t)f2bf(v.w) << 16);
    ((uint2*)out)[i] = make_uint2(lo, hi);
  }
}

// ---------------- RoPE cos/sin table ----------------
__global__ void rope_tab_kernel(float* __restrict__ tab) {
  int idx = blockIdx.x * blockDim.x + threadIdx.x;  // NT*64
  int t = idx >> 6, i = idx & 63;
  float inv = expf(-(float)(2 * i) * (9.210340371976184f / 128.f));
  float f = (float)t * inv;
  tab[t * 128 + i] = cosf(f);
  tab[t * 128 + 64 + i] = sinf(f);
}

// ---------------- RoPE apply + head split/transpose (Q and K only) ----------------
__global__ void rope_apply_kernel(const u16* __restrict__ qkv, const float* __restrict__ tab,
                                  u16* __restrict__ Q, u16* __restrict__ K) {
  int idx = blockIdx.x * blockDim.x + threadIdx.x;  // NB*NT*20*64
  int i = idx & 63;
  int rest = idx >> 6;
  int hh = rest % 20;
  int bt = rest / 20;
  int t = bt & (NT - 1);
  int b = bt >> 11;
  const u16* src_row = qkv + (long)bt * NQKV;
  float c = tab[t * 128 + i], s = tab[t * 128 + 64 + i];
  if (hh < NH) {
    const u16* sp = src_row + hh * HD;
    float x0 = bf2f(sp[i]), x1 = bf2f(sp[i + 64]);
    u16* dp = Q + ((long)(b * NH + hh) * NT + t) * HD;
    dp[i] = f2bf((x0 * c - x1 * s) * SCALE2);
    dp[i + 64] = f2bf((x1 * c + x0 * s) * SCALE2);
  } else {
    int kh = hh - NH;
    const u16* sp = src_row + (NH + kh) * HD;
    float x0 = bf2f(sp[i]), x1 = bf2f(sp[i + 64]);
    u16* dp = K + ((long)(b * NKV + kh) * NT + t) * HD;
    dp[i] = f2bf(x0 * c - x1 * s);
    dp[i + 64] = f2bf(x1 * c + x0 * s);
  }
}

// ---------------- V transpose to attn-ready layout ----------------
// Output Vt2[bkh][drow=d>>1][tile=t>>6][(d&1)*64 + pos] with pos = 16*(t'>>4) + sigma(t'&15)
// (t' = t&63), sigma = quad-swap (self-inverse), via swapping pk[2,3]<->pk[4,5].
__global__ void vtrans_kernel(const u16* __restrict__ qkv, u16* __restrict__ Vt) {
  __shared__ u16 tile[64][72];
  const int t0 = (blockIdx.x >> 1) * 64;
  const int d0 = (blockIdx.x & 1) * 64;
  const int bkh = blockIdx.y;                 // b*NKV + kh
  const int tid = threadIdx.x;
  const int tr = tid >> 2;
  const int tc = (tid & 3) * 16;
  const u16* src = qkv + ((long)((bkh >> 2) * NT) + t0 + tr) * NQKV +
                   (NH + NKV) * HD + (bkh & 3) * HD + d0 + tc;
  uint4 v0 = *(const uint4*)(src);
  uint4 v1 = *(const uint4*)(src + 8);
  *(uint4*)&tile[tr][tc] = v0;
  *(uint4*)&tile[tr][tc + 8] = v1;
  __syncthreads();
  const int dr = tid >> 2;
  const int tcc = (tid & 3) * 16;
  uint32_t pk[8];
#pragma unroll
  for (int e = 0; e < 8; ++e) {
    u16 a = tile[tcc + 2 * e][dr];
    u16 bq = tile[tcc + 2 * e + 1][dr];
    pk[e] = (uint32_t)a | ((uint32_t)bq << 16);
  }
  uint32_t tmp;
  tmp = pk[2]; pk[2] = pk[4]; pk[4] = tmp;
  tmp = pk[3]; pk[3] = pk[5]; pk[5] = tmp;
  const int d = d0 + dr;
  const int t = t0 + tcc;
  u16* dst = Vt + (long)bkh * HD * NT + (long)(d >> 1) * (2 * NT) +
             (t >> 6) * 128 + (d & 1) * 64 + (t & 48);
  *(uint4*)(dst) = *(uint4*)&pk[0];
  *(uint4*)(dst + 8) = *(uint4*)&pk[4];
}

// ---------------- GEMM v3: BM=256 x BN=(NREP*32), BK=64, counted-vmcnt pipeline ----------------
// NREP = per-wave N-fragment count. NREP=4 -> BN=128; NREP=6 -> BN=192 (gemm1 full-fill grid).
template <int OUT_BF16, int NREP>
__global__ __launch_bounds__(512, 1) void gemm256_kernel(const u16* __restrict__ A,
                                                         const u16* __restrict__ Bm,
                                                         void* __restrict__ Cm,
                                                         int M, int N, int K) {
  constexpr int BN = NREP * 32;
  __shared__ __align__(16) u16 As[2][256 * 64];   // 32 KB per buf
  __shared__ __align__(16) u16 Bs[2][BN * 64];    // 16 or 24 KB per buf
  const int tid = threadIdx.x, lane = tid & 63, wid = tid >> 6;
  const int wr = wid >> 1, wc = wid & 1;   // wave: 64 rows x (NREP*16) cols
  const int g = lane >> 4, r = lane & 15;
  const long row0 = (long)blockIdx.y * 256;
  const long col0 = (long)blockIdx.x * BN;
  const int lrow = lane >> 3;   // row within 8-row gload granule
  const int lch = lane & 7;     // 16B granule index within 128B row

  f32x4 acc[4][NREP] = {};

  auto stage = [&](int bufi, int kt) {
    const int k0 = kt * 64;
    u16* Ad = As[bufi];
    u16* Bd = Bs[bufi];
#pragma unroll
    for (int ii = 0; ii < 4; ++ii) {
      int rowl = wid * 32 + ii * 8 + lrow;
      const u16* src = A + (row0 + rowl) * (long)K + k0 + ((lch ^ (rowl & 7)) * 8);
      gload16(src, Ad + (wid * 32 + ii * 8) * 64);
    }
#pragma unroll
    for (int ii = 0; ii < NREP / 2; ++ii) {
      int rowl = wid * (NREP * 4) + ii * 8 + lrow;
      const u16* src = Bm + (col0 + rowl) * (long)K + k0 + ((lch ^ (rowl & 7)) * 8);
      gload16(src, Bd + (wid * (NREP * 4) + ii * 8) * 64);
    }
  };

  const int nt = K / 64;
  stage(0, 0);
  int buf = 0;
  for (int t = 0; t < nt; ++t) {
    if (t + 1 < nt) {
      stage(buf ^ 1, t + 1);
      __builtin_amdgcn_sched_barrier(0);
      if constexpr (NREP == 4) {
        asm volatile("s_waitcnt vmcnt(6)" ::: "memory");
      } else {
        asm volatile("s_waitcnt vmcnt(7)" ::: "memory");
      }
    } else {
      __builtin_amdgcn_sched_barrier(0);
      asm volatile("s_waitcnt vmcnt(0)" ::: "memory");
    }
    __builtin_amdgcn_sched_barrier(0);
    __builtin_amdgcn_s_barrier();
    __builtin_amdgcn_sched_barrier(0);

    const char* Ab = (const char*)As[buf];
    const char* Bb = (const char*)Bs[buf];
#pragma unroll
    for (int ks = 0; ks < 2; ++ks) {
      bf16x8 af[4], bfv[NREP];
#pragma unroll
      for (int mi = 0; mi < 4; ++mi) {
        int row = wr * 64 + mi * 16 + r;
        af[mi] = *(const bf16x8*)(Ab + row * 128 + (((4 * ks + g) ^ (row & 7)) * 16));
      }
#pragma unroll
      for (int ni = 0; ni < NREP; ++ni) {
        int row = wc * (NREP * 16) + ni * 16 + r;
        bfv[ni] = *(const bf16x8*)(Bb + row * 128 + (((4 * ks + g) ^ (row & 7)) * 16));
      }
      __builtin_amdgcn_s_setprio(1);
#pragma unroll
      for (int mi = 0; mi < 4; ++mi)
#pragma unroll
        for (int ni = 0; ni < NREP; ++ni)
          acc[mi][ni] = __builtin_amdgcn_mfma_f32_16x16x32_bf16(af[mi], bfv[ni], acc[mi][ni], 0, 0, 0);
      __builtin_amdgcn_s_setprio(0);
    }
    __builtin_amdgcn_sched_barrier(0);
    __builtin_amdgcn_s_barrier();
    __builtin_amdgcn_sched_barrier(0);
    buf ^= 1;
  }

#pragma unroll
  for (int mi = 0; mi < 4; ++mi)
#pragma unroll
    for (int ni = 0; ni < NREP; ++ni)
#pragma unroll
      for (int j = 0; j < 4; ++j) {
        long rr = row0 + wr * 64 + mi * 16 + g * 4 + j;
        long cc = col0 + wc * (NREP * 16) + ni * 16 + r;
        float v = acc[mi][ni][j];
        if (OUT_BF16) ((u16*)Cm)[rr * N + cc] = f2bf(v);
        else          ((float*)Cm)[rr * N + cc] = v;
      }
}

// ---------------- Flash attention v10 (round-15 best): 32x32 MFMA, register P, paired blocks ----------------
// Grid: 512 blocks (1D), 256 threads, (id, id+256) complementary q-tiles.
__global__ __launch_bounds__(256, 2) void attn_kernel(const u16* __restrict__ Qg,
                                                      const u16* __restrict__ Kg,
                                                      const u16* __restrict__ Vtg,
                                                      const float* __restrict__ amask,
                                                      u16* __restrict__ Y) {
  __shared__ __align__(16) u16 Ks[2][64 * 128];  // [kv][d], granule-swizzled ^(kv&15)
  __shared__ __align__(16) u16 Vs[2][64 * 128];  // [drow][256B], granule-swizzled ^(drow&15)
  const int tid = threadIdx.x, lane = tid & 63, wid = tid >> 6;
  const int ql = lane & 31, hi = lane >> 5;
  const int id = blockIdx.x;
  const int h = id & 15;
  const int xp = (id >> 4) & 7;
  const int b = (id >> 7) & 1;
  const int half = id >> 8;
  const int qt = half ? 15 - xp : xp;
  const int q0 = qt * 128;
  const int kh = h >> 2;

  const u16* Kbh = Kg + (long)(b * NKV + kh) * NT * HD;
  const u16* Vtbh = Vtg + (long)(b * NKV + kh) * HD * NT;
  const u16* Qbh = Qg + (long)(b * NH + h) * NT * HD;
  const float* am_b = amask + b * NT;

  const int total = 2 * qt + 2;  // causal KV-64 tiles for this q-tile

  const int srow = lane >> 4;    // 4 rows (256B each) per gload
  const int schunk = lane & 15;  // 16B granule within row
  auto stageK = [&](u16* dst, int kv0) {
#pragma unroll
    for (int ii = 0; ii < 4; ++ii) {
      int kvl = wid * 16 + ii * 4 + srow;
      const u16* src = Kbh + (long)(kv0 + kvl) * HD + ((schunk ^ (kvl & 15)) * 8);
      gload16(src, dst + (wid * 16 + ii * 4) * 128);
    }
  };
  auto stageV = [&](u16* dst, int kv0) {
    const u16* vb = Vtbh + (kv0 >> 6) * 128;
#pragma unroll
    for (int ii = 0; ii < 4; ++ii) {
      int R = wid * 16 + ii * 4 + srow;
      const u16* src = vb + (long)R * (2 * NT) + ((schunk ^ (R & 15)) * 8);
      gload16(src, dst + (wid * 16 + ii * 4) * 128);
    }
  };

  bf16x8 qf[8];
  {
    const u16* Qrow = Qbh + (long)(q0 + wid * 32 + ql) * HD;
#pragma unroll
    for (int ks = 0; ks < 8; ++ks)
      qf[ks] = *(const bf16x8*)(Qrow + ks * 16 + 8 * hi);
  }

  // ---- prologue ----
  stageK(Ks[0], 0);
  stageV(Vs[0], 0);
  __syncthreads();

  float m = -INFINITY;
  f32x4 lacc = {};
  f32x16 o[4] = {};
  int buf = 0;
  const int qi = q0 + wid * 32 + ql;

  for (int i = 0; i < total; ++i) {
    const int kv0 = i * 64;

    if (i + 1 < total) {
      stageK(Ks[buf ^ 1], (i + 1) * 64);
      stageV(Vs[buf ^ 1], (i + 1) * 64);
    }

    const char* Ksb = (const char*)Ks[buf];
    const char* Vsb = (const char*)Vs[buf];

    // ---- S^T = mfma(K, Q): 4 independent chains of 4 (split accumulators) ----
    f32x16 s0a = {}, s0b = {}, s1a = {}, s1b = {};
    __builtin_amdgcn_s_setprio(1);
#pragma unroll
    for (int ks = 0; ks < 4; ++ks) {
      bf16x8 kf0 = *(const bf16x8*)(Ksb + ql * 256 + (((2 * ks + hi) ^ (ql & 15)) * 16));
      bf16x8 kf1 = *(const bf16x8*)(Ksb + (32 + ql) * 256 + (((2 * ks + hi) ^ (ql & 15)) * 16));
      s0a = __builtin_amdgcn_mfma_f32_32x32x16_bf16(kf0, qf[ks], s0a, 0, 0, 0);
      s1a = __builtin_amdgcn_mfma_f32_32x32x16_bf16(kf1, qf[ks], s1a, 0, 0, 0);
    }
#pragma unroll
    for (int ks = 4; ks < 8; ++ks) {
      bf16x8 kf0 = *(const bf16x8*)(Ksb + ql * 256 + (((2 * ks + hi) ^ (ql & 15)) * 16));
      bf16x8 kf1 = *(const bf16x8*)(Ksb + (32 + ql) * 256 + (((2 * ks + hi) ^ (ql & 15)) * 16));
      s0b = __builtin_amdgcn_mfma_f32_32x32x16_bf16(kf0, qf[ks], s0b, 0, 0, 0);
      s1b = __builtin_amdgcn_mfma_f32_32x32x16_bf16(kf1, qf[ks], s1b, 0, 0, 0);
    }
    __builtin_amdgcn_s_setprio(0);
    f32x16 s0 = s0a + s0b;
    f32x16 s1 = s1a + s1b;

    // ---- causal mask (tiles overlapping the diagonal zone) ----
    if (i >= 2 * qt) {
#pragma unroll
      for (int reg = 0; reg < 16; ++reg) {
        int kvl = (reg & 3) + 8 * (reg >> 2) + 4 * hi;
        if (kv0 + kvl > qi) s0[reg] = -INFINITY;
        if (kv0 + 32 + kvl > qi) s1[reg] = -INFINITY;
      }
    }

    // ---- defer-max: explicit binary tree (depth 5), wave-uniform check, no shfl ----
    float t16[16];
#pragma unroll
    for (int reg = 0; reg < 16; ++reg) t16[reg] = fmaxf(s0[reg], s1[reg]);
    float t8[8];
#pragma unroll
    for (int reg = 0; reg < 8; ++reg) t8[reg] = fmaxf(t16[reg], t16[reg + 8]);
    float t4[4];
#pragma unroll
    for (int reg = 0; reg < 4; ++reg) t4[reg] = fmaxf(t8[reg], t8[reg + 4]);
    float mxl = fmaxf(fmaxf(t4[0], t4[1]), fmaxf(t4[2], t4[3]));
    if (!__all(mxl <= m + 8.f)) {
      float mx = fmaxf(mxl, __shfl_xor(mxl, 32));
      float mnew = fmaxf(m, mx);
      float alpha = exp2f(m - mnew);
      m = mnew;
      lacc *= alpha;
#pragma unroll
      for (int dblk = 0; dblk < 4; ++dblk) o[dblk] *= alpha;
    }

    // ---- P = exp2(S - m) * mask (in place) ----
    float4 am0[4], am1[4];
#pragma unroll
    for (int uu = 0; uu < 4; ++uu) {
      am0[uu] = *(const float4*)(am_b + kv0 + 8 * uu + 4 * hi);
      am1[uu] = *(const float4*)(am_b + kv0 + 32 + 8 * uu + 4 * hi);
    }
#pragma unroll
    for (int reg = 0; reg < 16; ++reg) {
      float p0 = exp2f(s0[reg] - m) * (&am0[reg >> 2].x)[reg & 3];
      float p1 = exp2f(s1[reg] - m) * (&am1[reg >> 2].x)[reg & 3];
      s0[reg] = p0; s1[reg] = p1;
      lacc[reg & 3] += p0 + p1;
    }

    // ---- pack P fragments from own regs (sigma-matched, no LDS) ----
    bf16x8 pb[4];
#pragma unroll
    for (int ks = 0; ks < 4; ++ks) {
      union { __bf16 hh[8]; bf16x8 v; } pk;
      const int base = 8 * (ks & 1);
#pragma unroll
      for (int j = 0; j < 8; ++j)
        pk.hh[j] = (__bf16)((ks >= 2) ? s1[base + j] : s0[base + j]);
      pb[ks] = pk.v;
    }

    // ---- O^T += mfma(V^T, P): A row d = 32*dblk + ql (4 independent chains) ----
    __builtin_amdgcn_s_setprio(1);
#pragma unroll
    for (int ks = 0; ks < 4; ++ks) {
#pragma unroll
      for (int dblk = 0; dblk < 4; ++dblk) {
        int drow = dblk * 16 + (ql >> 1);
        int gr = ((ql & 1) * 8 + 2 * ks + hi) ^ (drow & 15);
        bf16x8 va = *(const bf16x8*)(Vsb + drow * 256 + gr * 16);
        o[dblk] = __builtin_amdgcn_mfma_f32_32x32x16_bf16(va, pb[ks], o[dblk], 0, 0, 0);
      }
    }
    __builtin_amdgcn_s_setprio(0);

    __syncthreads();
    buf ^= 1;
  }

  // ---- epilogue: reduce l once, write Y ----
  {
    float l = (lacc[0] + lacc[1]) + (lacc[2] + lacc[3]);
    l += __shfl_xor(l, 32);
    float invl = 1.f / l;
    u16* Yrow = Y + ((long)b * NT + qi) * NC + h * HD;
#pragma unroll
    for (int dblk = 0; dblk < 4; ++dblk)
#pragma unroll
      for (int uu = 0; uu < 4; ++uu) {
        int d = dblk * 32 + 8 * uu + 4 * hi;
        int r0 = 4 * uu;
        *(uint2*)(Yrow + d) = make_uint2(
            packbf2(o[dblk][r0] * invl, o[dblk][r0 + 1] * invl),
            packbf2(o[dblk][r0 + 2] * invl, o[dblk][r0 + 3] * invl));
      }
  }
}

extern "C" void kernel_launch(void* const* d_in, const int* in_sizes, int n_in,
                              void* d_out, int out_size, void* d_ws, size_t ws_size,
                              hipStream_t stream) {
  const float* x = (const float*)d_in[0];
  const float* amask = (const float*)d_in[1];
  const float* w_qkv = (const float*)d_in[2];
  const float* w_proj = (const float*)d_in[3];

  const long MT = (long)NB * NT;  // 4096
  char* ws = (char*)d_ws;
  size_t off = 0;
  auto carve = [&](size_t bytes) -> char* {
    char* p = ws + off;
    off += (bytes + 255) & ~(size_t)255;
    return p;
  };
  u16* xb   = (u16*)carve((size_t)MT * NC * 2);       // A for gemm1; later Q
  u16* wqb  = (u16*)carve((size_t)NQKV * NC * 2);     // B for gemm1; later K + Vt
  u16* wpb  = (u16*)carve((size_t)NC * NC * 2);       // B for gemm2
  u16* qkvb = (u16*)carve((size_t)MT * NQKV * 2);     // C of gemm1; later Y
  float* tab = (float*)carve((size_t)NT * 128 * 4);

  u16* Qb = xb;
  u16* Kb = wqb;
  u16* Vtb = wqb + (size_t)NB * NKV * NT * HD;
  u16* Yb = qkvb;

  // Single fused conversion: x, w_qkv, w_proj are consecutive input regions converted
  // into the consecutive ws carves (xb, wqb, wpb are contiguous modulo 256B alignment —
  // all three sizes are 256B multiples, so xb..wpb is one contiguous run; likewise we
  // convert each tensor separately only if inputs aren't contiguous. Inputs are separate
  // allocations, so keep 3 calls but grid-stride with capped grids to cut tail waste.
  {
    int n4 = (int)(MT * NC / 4);
    cvt_bf16_kernel<<<dim3(2048), dim3(256), 0, stream>>>(x, xb, n4);
    n4 = (int)((long)NQKV * NC / 4);
    cvt_bf16_kernel<<<dim3(2048), dim3(256), 0, stream>>>(w_qkv, wqb, n4);
    n4 = (int)((long)NC * NC / 4);
    cvt_bf16_kernel<<<dim3(2048), dim3(256), 0, stream>>>(w_proj, wpb, n4);
  }
  rope_tab_kernel<<<dim3(NT * 64 / 256), dim3(256), 0, stream>>>(tab);
  gemm256_kernel<1, 6><<<dim3(NQKV / 192, MT / 256), dim3(512), 0, stream>>>(xb, wqb, qkvb, (int)MT, NQKV, NC);
  rope_apply_kernel<<<dim3(NB * NT * 20 * 64 / 256), dim3(256), 0, stream>>>(qkvb, tab, Qb, Kb);
  vtrans_kernel<<<dim3(NT / 64 * 2, NB * NKV), dim3(256), 0, stream>>>(qkvb, Vtb);
  attn_kernel<<<dim3(512), dim3(256), 0, stream>>>(Qb, Kb, Vtb, amask, Yb);
  gemm256_kernel<0, 4><<<dim3(NC / 128, MT / 256), dim3(512), 0, stream>>>(Yb, wpb, d_out, (int)MT, NC, NC);
}

// Round 19
// 196.294 us; speedup vs baseline: 1.1034x; 1.0136x over previous
//
#include <hip/hip_runtime.h>
#include <hip/hip_bf16.h>
#include <stdint.h>

typedef unsigned short u16;
typedef __attribute__((ext_vector_type(4))) float f32x4;
typedef __attribute__((ext_vector_type(16))) float f32x16;
typedef __attribute__((ext_vector_type(8))) __bf16 bf16x8;

#define NB 2
#define NT 2048
#define NC 2048
#define NH 16
#define NKV 4
#define HD 128
#define NQKV 3072
#define SCALE2 0.12751739f  // (1/sqrt(128)) * log2(e)

__device__ __forceinline__ u16 f2bf(float f) {
  union { float f; uint32_t u; } c; c.f = f;
  uint32_t u = c.u + 0x7fffu + ((c.u >> 16) & 1u);
  return (u16)(u >> 16);
}
__device__ __forceinline__ float bf2f(u16 h) {
  union { uint32_t u; float f; } c; c.u = ((uint32_t)h) << 16;
  return c.f;
}
__device__ __forceinline__ uint32_t packbf2(float a, float b) {
  return (uint32_t)f2bf(a) | ((uint32_t)f2bf(b) << 16);
}

// global -> LDS async copy, 16B per lane. LDS dest = wave-uniform base + lane*16.
__device__ __forceinline__ void gload16(const void* g, void* lds) {
  __builtin_amdgcn_global_load_lds(
      (__attribute__((address_space(1))) void*)(uintptr_t)g,
      (__attribute__((address_space(3))) void*)(uint32_t)(uintptr_t)lds,
      16, 0, 0);
}

// ---------------- fp32 -> bf16 convert, grid-stride ----------------
__global__ void cvt_bf16_kernel(const float* __restrict__ in, u16* __restrict__ out, int n4) {
  int stride = gridDim.x * blockDim.x;
  for (int i = blockIdx.x * blockDim.x + threadIdx.x; i < n4; i += stride) {
    float4 v = ((const float4*)in)[i];
    uint32_t lo = (uint32_t)f2bf(v.x) | ((uint32_t)f2bf(v.y) << 16);
    uint32_t hi = (uint32_t)f2bf(v.z) | ((uint32_t)f2bf(v.w) << 16);
    ((uint2*)out)[i] = make_uint2(lo, hi);
  }
}

// ---------------- RoPE cos/sin table ----------------
__global__ void rope_tab_kernel(float* __restrict__ tab) {
  int idx = blockIdx.x * blockDim.x + threadIdx.x;  // NT*64
  int t = idx >> 6, i = idx & 63;
  float inv = expf(-(float)(2 * i) * (9.210340371976184f / 128.f));
  float f = (float)t * inv;
  tab[t * 128 + i] = cosf(f);
  tab[t * 128 + 64 + i] = sinf(f);
}

// ---------------- RoPE apply + head split/transpose (Q and K only) ----------------
__global__ void rope_apply_kernel(const u16* __restrict__ qkv, const float* __restrict__ tab,
                                  u16* __restrict__ Q, u16* __restrict__ K) {
  int idx = blockIdx.x * blockDim.x + threadIdx.x;  // NB*NT*20*64
  int i = idx & 63;
  int rest = idx >> 6;
  int hh = rest % 20;
  int bt = rest / 20;
  int t = bt & (NT - 1);
  int b = bt >> 11;
  const u16* src_row = qkv + (long)bt * NQKV;
  float c = tab[t * 128 + i], s = tab[t * 128 + 64 + i];
  if (hh < NH) {
    const u16* sp = src_row + hh * HD;
    float x0 = bf2f(sp[i]), x1 = bf2f(sp[i + 64]);
    u16* dp = Q + ((long)(b * NH + hh) * NT + t) * HD;
    dp[i] = f2bf((x0 * c - x1 * s) * SCALE2);
    dp[i + 64] = f2bf((x1 * c + x0 * s) * SCALE2);
  } else {
    int kh = hh - NH;
    const u16* sp = src_row + (NH + kh) * HD;
    float x0 = bf2f(sp[i]), x1 = bf2f(sp[i + 64]);
    u16* dp = K + ((long)(b * NKV + kh) * NT + t) * HD;
    dp[i] = f2bf(x0 * c - x1 * s);
    dp[i + 64] = f2bf(x1 * c + x0 * s);
  }
}

// ---------------- V transpose to attn-ready layout ----------------
__global__ void vtrans_kernel(const u16* __restrict__ qkv, u16* __restrict__ Vt) {
  __shared__ u16 tile[64][72];
  const int t0 = (blockIdx.x >> 1) * 64;
  const int d0 = (blockIdx.x & 1) * 64;
  const int bkh = blockIdx.y;                 // b*NKV + kh
  const int tid = threadIdx.x;
  const int tr = tid >> 2;
  const int tc = (tid & 3) * 16;
  const u16* src = qkv + ((long)((bkh >> 2) * NT) + t0 + tr) * NQKV +
                   (NH + NKV) * HD + (bkh & 3) * HD + d0 + tc;
  uint4 v0 = *(const uint4*)(src);
  uint4 v1 = *(const uint4*)(src + 8);
  *(uint4*)&tile[tr][tc] = v0;
  *(uint4*)&tile[tr][tc + 8] = v1;
  __syncthreads();
  const int dr = tid >> 2;
  const int tcc = (tid & 3) * 16;
  uint32_t pk[8];
#pragma unroll
  for (int e = 0; e < 8; ++e) {
    u16 a = tile[tcc + 2 * e][dr];
    u16 bq = tile[tcc + 2 * e + 1][dr];
    pk[e] = (uint32_t)a | ((uint32_t)bq << 16);
  }
  uint32_t tmp;
  tmp = pk[2]; pk[2] = pk[4]; pk[4] = tmp;
  tmp = pk[3]; pk[3] = pk[5]; pk[5] = tmp;
  const int d = d0 + dr;
  const int t = t0 + tcc;
  u16* dst = Vt + (long)bkh * HD * NT + (long)(d >> 1) * (2 * NT) +
             (t >> 6) * 128 + (d & 1) * 64 + (t & 48);
  *(uint4*)(dst) = *(uint4*)&pk[0];
  *(uint4*)(dst + 8) = *(uint4*)&pk[4];
}

// ---------------- GEMM v4: BM=256 x BN=(NREP*32), BK=64, phase-split + counted vmcnt + XCD swizzle ----------------
// Per K-tile: [stageA(t+1): 4 gloads][vmcnt(4)][bar][ds ks=0 + MFMA][bar]
//             [stageB(t+1): NREP/2 gloads][ds ks=1 + MFMA][bar]
// vmcnt(4) allows stageA(t+1) in flight while forcing stage(t) landed.
template <int OUT_BF16, int NREP>
__global__ __launch_bounds__(512, 1) void gemm256_kernel(const u16* __restrict__ A,
                                                         const u16* __restrict__ Bm,
                                                         void* __restrict__ Cm,
                                                         int M, int N, int K) {
  constexpr int BN = NREP * 32;
  __shared__ __align__(16) u16 As[2][256 * 64];   // 32 KB per buf
  __shared__ __align__(16) u16 Bs[2][BN * 64];    // 16 or 24 KB per buf
  const int tid = threadIdx.x, lane = tid & 63, wid = tid >> 6;
  const int wr = wid >> 1, wc = wid & 1;   // wave: 64 rows x (NREP*16) cols
  const int g = lane >> 4, r = lane & 15;
  // XCD-aware bijective swizzle (T1): grids are 256 blocks = 8 XCDs x 32 contiguous tiles.
  int lin = blockIdx.y * gridDim.x + blockIdx.x;
  const int nwg = gridDim.x * gridDim.y;
  lin = (lin & 7) * (nwg >> 3) + (lin >> 3);
  const int bx = lin % gridDim.x;
  const int by = lin / gridDim.x;
  const long row0 = (long)by * 256;
  const long col0 = (long)bx * BN;
  const int lrow = lane >> 3;   // row within 8-row gload granule
  const int lch = lane & 7;     // 16B granule index within 128B row

  f32x4 acc[4][NREP] = {};

  auto stageA = [&](int bufi, int kt) {
    const int k0 = kt * 64;
    u16* Ad = As[bufi];
#pragma unroll
    for (int ii = 0; ii < 4; ++ii) {
      int rowl = wid * 32 + ii * 8 + lrow;
      const u16* src = A + (row0 + rowl) * (long)K + k0 + ((lch ^ (rowl & 7)) * 8);
      gload16(src, Ad + (wid * 32 + ii * 8) * 64);
    }
  };
  auto stageB = [&](int bufi, int kt) {
    const int k0 = kt * 64;
    u16* Bd = Bs[bufi];
#pragma unroll
    for (int ii = 0; ii < NREP / 2; ++ii) {
      int rowl = wid * (NREP * 4) + ii * 8 + lrow;
      const u16* src = Bm + (col0 + rowl) * (long)K + k0 + ((lch ^ (rowl & 7)) * 8);
      gload16(src, Bd + (wid * (NREP * 4) + ii * 8) * 64);
    }
  };

  const int nt = K / 64;
  stageA(0, 0);
  stageB(0, 0);
  int buf = 0;
  for (int t = 0; t < nt; ++t) {
    const char* Ab = (const char*)As[buf];
    const char* Bb = (const char*)Bs[buf];

    // ---- Phase A: issue A-half of next stage, wait counted, compute ks=0 ----
    if (t + 1 < nt) {
      stageA(buf ^ 1, t + 1);
      __builtin_amdgcn_sched_barrier(0);
      asm volatile("s_waitcnt vmcnt(4)" ::: "memory");  // stage(t) landed; A(t+1) in flight
    } else {
      __builtin_amdgcn_sched_barrier(0);
      asm volatile("s_waitcnt vmcnt(0)" ::: "memory");
    }
    __builtin_amdgcn_sched_barrier(0);
    __builtin_amdgcn_s_barrier();
    __builtin_amdgcn_sched_barrier(0);
    {
      bf16x8 af[4], bfv[NREP];
#pragma unroll
      for (int mi = 0; mi < 4; ++mi) {
        int row = wr * 64 + mi * 16 + r;
        af[mi] = *(const bf16x8*)(Ab + row * 128 + ((g ^ (row & 7)) * 16));
      }
#pragma unroll
      for (int ni = 0; ni < NREP; ++ni) {
        int row = wc * (NREP * 16) + ni * 16 + r;
        bfv[ni] = *(const bf16x8*)(Bb + row * 128 + ((g ^ (row & 7)) * 16));
      }
      __builtin_amdgcn_s_setprio(1);
#pragma unroll
      for (int mi = 0; mi < 4; ++mi)
#pragma unroll
        for (int ni = 0; ni < NREP; ++ni)
          acc[mi][ni] = __builtin_amdgcn_mfma_f32_16x16x32_bf16(af[mi], bfv[ni], acc[mi][ni], 0, 0, 0);
      __builtin_amdgcn_s_setprio(0);
    }
    __builtin_amdgcn_sched_barrier(0);
    __builtin_amdgcn_s_barrier();
    __builtin_amdgcn_sched_barrier(0);

    // ---- Phase B: issue B-half of next stage, compute ks=1 ----
    if (t + 1 < nt) stageB(buf ^ 1, t + 1);
    __builtin_amdgcn_sched_barrier(0);
    {
      bf16x8 af[4], bfv[NREP];
#pragma unroll
      for (int mi = 0; mi < 4; ++mi) {
        int row = wr * 64 + mi * 16 + r;
        af[mi] = *(const bf16x8*)(Ab + row * 128 + (((4 + g) ^ (row & 7)) * 16));
      }
#pragma unroll
      for (int ni = 0; ni < NREP; ++ni) {
        int row = wc * (NREP * 16) + ni * 16 + r;
        bfv[ni] = *(const bf16x8*)(Bb + row * 128 + (((4 + g) ^ (row & 7)) * 16));
      }
      __builtin_amdgcn_s_setprio(1);
#pragma unroll
      for (int mi = 0; mi < 4; ++mi)
#pragma unroll
        for (int ni = 0; ni < NREP; ++ni)
          acc[mi][ni] = __builtin_amdgcn_mfma_f32_16x16x32_bf16(af[mi], bfv[ni], acc[mi][ni], 0, 0, 0);
      __builtin_amdgcn_s_setprio(0);
    }
    __builtin_amdgcn_sched_barrier(0);
    __builtin_amdgcn_s_barrier();
    __builtin_amdgcn_sched_barrier(0);
    buf ^= 1;
  }

#pragma unroll
  for (int mi = 0; mi < 4; ++mi)
#pragma unroll
    for (int ni = 0; ni < NREP; ++ni)
#pragma unroll
      for (int j = 0; j < 4; ++j) {
        long rr = row0 + wr * 64 + mi * 16 + g * 4 + j;
        long cc = col0 + wc * (NREP * 16) + ni * 16 + r;
        float v = acc[mi][ni][j];
        if (OUT_BF16) ((u16*)Cm)[rr * N + cc] = f2bf(v);
        else          ((float*)Cm)[rr * N + cc] = v;
      }
}

// ---------------- Flash attention v10 (round-15 best): 32x32 MFMA, register P, paired blocks ----------------
__global__ __launch_bounds__(256, 2) void attn_kernel(const u16* __restrict__ Qg,
                                                      const u16* __restrict__ Kg,
                                                      const u16* __restrict__ Vtg,
                                                      const float* __restrict__ amask,
                                                      u16* __restrict__ Y) {
  __shared__ __align__(16) u16 Ks[2][64 * 128];  // [kv][d], granule-swizzled ^(kv&15)
  __shared__ __align__(16) u16 Vs[2][64 * 128];  // [drow][256B], granule-swizzled ^(drow&15)
  const int tid = threadIdx.x, lane = tid & 63, wid = tid >> 6;
  const int ql = lane & 31, hi = lane >> 5;
  const int id = blockIdx.x;
  const int h = id & 15;
  const int xp = (id >> 4) & 7;
  const int b = (id >> 7) & 1;
  const int half = id >> 8;
  const int qt = half ? 15 - xp : xp;
  const int q0 = qt * 128;
  const int kh = h >> 2;

  const u16* Kbh = Kg + (long)(b * NKV + kh) * NT * HD;
  const u16* Vtbh = Vtg + (long)(b * NKV + kh) * HD * NT;
  const u16* Qbh = Qg + (long)(b * NH + h) * NT * HD;
  const float* am_b = amask + b * NT;

  const int total = 2 * qt + 2;  // causal KV-64 tiles for this q-tile

  const int srow = lane >> 4;    // 4 rows (256B each) per gload
  const int schunk = lane & 15;  // 16B granule within row
  auto stageK = [&](u16* dst, int kv0) {
#pragma unroll
    for (int ii = 0; ii < 4; ++ii) {
      int kvl = wid * 16 + ii * 4 + srow;
      const u16* src = Kbh + (long)(kv0 + kvl) * HD + ((schunk ^ (kvl & 15)) * 8);
      gload16(src, dst + (wid * 16 + ii * 4) * 128);
    }
  };
  auto stageV = [&](u16* dst, int kv0) {
    const u16* vb = Vtbh + (kv0 >> 6) * 128;
#pragma unroll
    for (int ii = 0; ii < 4; ++ii) {
      int R = wid * 16 + ii * 4 + srow;
      const u16* src = vb + (long)R * (2 * NT) + ((schunk ^ (R & 15)) * 8);
      gload16(src, dst + (wid * 16 + ii * 4) * 128);
    }
  };

  bf16x8 qf[8];
  {
    const u16* Qrow = Qbh + (long)(q0 + wid * 32 + ql) * HD;
#pragma unroll
    for (int ks = 0; ks < 8; ++ks)
      qf[ks] = *(const bf16x8*)(Qrow + ks * 16 + 8 * hi);
  }

  // ---- prologue ----
  stageK(Ks[0], 0);
  stageV(Vs[0], 0);
  __syncthreads();

  float m = -INFINITY;
  f32x4 lacc = {};
  f32x16 o[4] = {};
  int buf = 0;
  const int qi = q0 + wid * 32 + ql;

  for (int i = 0; i < total; ++i) {
    const int kv0 = i * 64;

    if (i + 1 < total) {
      stageK(Ks[buf ^ 1], (i + 1) * 64);
      stageV(Vs[buf ^ 1], (i + 1) * 64);
    }

    const char* Ksb = (const char*)Ks[buf];
    const char* Vsb = (const char*)Vs[buf];

    // ---- S^T = mfma(K, Q): 4 independent chains of 4 (split accumulators) ----
    f32x16 s0a = {}, s0b = {}, s1a = {}, s1b = {};
    __builtin_amdgcn_s_setprio(1);
#pragma unroll
    for (int ks = 0; ks < 4; ++ks) {
      bf16x8 kf0 = *(const bf16x8*)(Ksb + ql * 256 + (((2 * ks + hi) ^ (ql & 15)) * 16));
      bf16x8 kf1 = *(const bf16x8*)(Ksb + (32 + ql) * 256 + (((2 * ks + hi) ^ (ql & 15)) * 16));
      s0a = __builtin_amdgcn_mfma_f32_32x32x16_bf16(kf0, qf[ks], s0a, 0, 0, 0);
      s1a = __builtin_amdgcn_mfma_f32_32x32x16_bf16(kf1, qf[ks], s1a, 0, 0, 0);
    }
#pragma unroll
    for (int ks = 4; ks < 8; ++ks) {
      bf16x8 kf0 = *(const bf16x8*)(Ksb + ql * 256 + (((2 * ks + hi) ^ (ql & 15)) * 16));
      bf16x8 kf1 = *(const bf16x8*)(Ksb + (32 + ql) * 256 + (((2 * ks + hi) ^ (ql & 15)) * 16));
      s0b = __builtin_amdgcn_mfma_f32_32x32x16_bf16(kf0, qf[ks], s0b, 0, 0, 0);
      s1b = __builtin_amdgcn_mfma_f32_32x32x16_bf16(kf1, qf[ks], s1b, 0, 0, 0);
    }
    __builtin_amdgcn_s_setprio(0);
    f32x16 s0 = s0a + s0b;
    f32x16 s1 = s1a + s1b;

    // ---- causal mask (tiles overlapping the diagonal zone) ----
    if (i >= 2 * qt) {
#pragma unroll
      for (int reg = 0; reg < 16; ++reg) {
        int kvl = (reg & 3) + 8 * (reg >> 2) + 4 * hi;
        if (kv0 + kvl > qi) s0[reg] = -INFINITY;
        if (kv0 + 32 + kvl > qi) s1[reg] = -INFINITY;
      }
    }

    // ---- defer-max: explicit binary tree (depth 5), wave-uniform check, no shfl ----
    float t16[16];
#pragma unroll
    for (int reg = 0; reg < 16; ++reg) t16[reg] = fmaxf(s0[reg], s1[reg]);
    float t8[8];
#pragma unroll
    for (int reg = 0; reg < 8; ++reg) t8[reg] = fmaxf(t16[reg], t16[reg + 8]);
    float t4[4];
#pragma unroll
    for (int reg = 0; reg < 4; ++reg) t4[reg] = fmaxf(t8[reg], t8[reg + 4]);
    float mxl = fmaxf(fmaxf(t4[0], t4[1]), fmaxf(t4[2], t4[3]));
    if (!__all(mxl <= m + 8.f)) {
      float mx = fmaxf(mxl, __shfl_xor(mxl, 32));
      float mnew = fmaxf(m, mx);
      float alpha = exp2f(m - mnew);
      m = mnew;
      lacc *= alpha;
#pragma unroll
      for (int dblk = 0; dblk < 4; ++dblk) o[dblk] *= alpha;
    }

    // ---- P = exp2(S - m) * mask (in place) ----
    float4 am0[4], am1[4];
#pragma unroll
    for (int uu = 0; uu < 4; ++uu) {
      am0[uu] = *(const float4*)(am_b + kv0 + 8 * uu + 4 * hi);
      am1[uu] = *(const float4*)(am_b + kv0 + 32 + 8 * uu + 4 * hi);
    }
#pragma unroll
    for (int reg = 0; reg < 16; ++reg) {
      float p0 = exp2f(s0[reg] - m) * (&am0[reg >> 2].x)[reg & 3];
      float p1 = exp2f(s1[reg] - m) * (&am1[reg >> 2].x)[reg & 3];
      s0[reg] = p0; s1[reg] = p1;
      lacc[reg & 3] += p0 + p1;
    }

    // ---- pack P fragments from own regs (sigma-matched, no LDS) ----
    bf16x8 pb[4];
#pragma unroll
    for (int ks = 0; ks < 4; ++ks) {
      union { __bf16 hh[8]; bf16x8 v; } pk;
      const int base = 8 * (ks & 1);
#pragma unroll
      for (int j = 0; j < 8; ++j)
        pk.hh[j] = (__bf16)((ks >= 2) ? s1[base + j] : s0[base + j]);
      pb[ks] = pk.v;
    }

    // ---- O^T += mfma(V^T, P): A row d = 32*dblk + ql (4 independent chains) ----
    __builtin_amdgcn_s_setprio(1);
#pragma unroll
    for (int ks = 0; ks < 4; ++ks) {
#pragma unroll
      for (int dblk = 0; dblk < 4; ++dblk) {
        int drow = dblk * 16 + (ql >> 1);
        int gr = ((ql & 1) * 8 + 2 * ks + hi) ^ (drow & 15);
        bf16x8 va = *(const bf16x8*)(Vsb + drow * 256 + gr * 16);
        o[dblk] = __builtin_amdgcn_mfma_f32_32x32x16_bf16(va, pb[ks], o[dblk], 0, 0, 0);
      }
    }
    __builtin_amdgcn_s_setprio(0);

    __syncthreads();
    buf ^= 1;
  }

  // ---- epilogue: reduce l once, write Y ----
  {
    float l = (lacc[0] + lacc[1]) + (lacc[2] + lacc[3]);
    l += __shfl_xor(l, 32);
    float invl = 1.f / l;
    u16* Yrow = Y + ((long)b * NT + qi) * NC + h * HD;
#pragma unroll
    for (int dblk = 0; dblk < 4; ++dblk)
#pragma unroll
      for (int uu = 0; uu < 4; ++uu) {
        int d = dblk * 32 + 8 * uu + 4 * hi;
        int r0 = 4 * uu;
        *(uint2*)(Yrow + d) = make_uint2(
            packbf2(o[dblk][r0] * invl, o[dblk][r0 + 1] * invl),
            packbf2(o[dblk][r0 + 2] * invl, o[dblk][r0 + 3] * invl));
      }
  }
}

extern "C" void kernel_launch(void* const* d_in, const int* in_sizes, int n_in,
                              void* d_out, int out_size, void* d_ws, size_t ws_size,
                              hipStream_t stream) {
  const float* x = (const float*)d_in[0];
  const float* amask = (const float*)d_in[1];
  const float* w_qkv = (const float*)d_in[2];
  const float* w_proj = (const float*)d_in[3];

  const long MT = (long)NB * NT;  // 4096
  char* ws = (char*)d_ws;
  size_t off = 0;
  auto carve = [&](size_t bytes) -> char* {
    char* p = ws + off;
    off += (bytes + 255) & ~(size_t)255;
    return p;
  };
  u16* xb   = (u16*)carve((size_t)MT * NC * 2);       // A for gemm1; later Q
  u16* wqb  = (u16*)carve((size_t)NQKV * NC * 2);     // B for gemm1; later K + Vt
  u16* wpb  = (u16*)carve((size_t)NC * NC * 2);       // B for gemm2
  u16* qkvb = (u16*)carve((size_t)MT * NQKV * 2);     // C of gemm1; later Y
  float* tab = (float*)carve((size_t)NT * 128 * 4);

  u16* Qb = xb;
  u16* Kb = wqb;
  u16* Vtb = wqb + (size_t)NB * NKV * NT * HD;
  u16* Yb = qkvb;

  {
    int n4 = (int)(MT * NC / 4);
    cvt_bf16_kernel<<<dim3(2048), dim3(256), 0, stream>>>(x, xb, n4);
    n4 = (int)((long)NQKV * NC / 4);
    cvt_bf16_kernel<<<dim3(2048), dim3(256), 0, stream>>>(w_qkv, wqb, n4);
    n4 = (int)((long)NC * NC / 4);
    cvt_bf16_kernel<<<dim3(2048), dim3(256), 0, stream>>>(w_proj, wpb, n4);
  }
  rope_tab_kernel<<<dim3(NT * 64 / 256), dim3(256), 0, stream>>>(tab);
  gemm256_kernel<1, 6><<<dim3(NQKV / 192, MT / 256), dim3(512), 0, stream>>>(xb, wqb, qkvb, (int)MT, NQKV, NC);
  rope_apply_kernel<<<dim3(NB * NT * 20 * 64 / 256), dim3(256), 0, stream>>>(qkvb, tab, Qb, Kb);
  vtrans_kernel<<<dim3(NT / 64 * 2, NB * NKV), dim3(256), 0, stream>>>(qkvb, Vtb);
  attn_kernel<<<dim3(512), dim3(256), 0, stream>>>(Qb, Kb, Vtb, amask, Yb);
  gemm256_kernel<0, 4><<<dim3(NC / 128, MT / 256), dim3(512), 0, stream>>>(Yb, wpb, d_out, (int)MT, NC, NC);
}

// Round 20
// 194.999 us; speedup vs baseline: 1.1108x; 1.0066x over previous
//
#include <hip/hip_runtime.h>
#include <hip/hip_bf16.h>
#include <stdint.h>

typedef unsigned short u16;
typedef __attribute__((ext_vector_type(4))) float f32x4;
typedef __attribute__((ext_vector_type(16))) float f32x16;
typedef __attribute__((ext_vector_type(8))) __bf16 bf16x8;

#define NB 2
#define NT 2048
#define NC 2048
#define NH 16
#define NKV 4
#define HD 128
#define NQKV 3072
#define SCALE2 0.12751739f  // (1/sqrt(128)) * log2(e)

__device__ __forceinline__ u16 f2bf(float f) {
  union { float f; uint32_t u; } c; c.f = f;
  uint32_t u = c.u + 0x7fffu + ((c.u >> 16) & 1u);
  return (u16)(u >> 16);
}
__device__ __forceinline__ float bf2f(u16 h) {
  union { uint32_t u; float f; } c; c.u = ((uint32_t)h) << 16;
  return c.f;
}
__device__ __forceinline__ uint32_t packbf2(float a, float b) {
  return (uint32_t)f2bf(a) | ((uint32_t)f2bf(b) << 16);
}

// global -> LDS async copy, 16B per lane. LDS dest = wave-uniform base + lane*16.
__device__ __forceinline__ void gload16(const void* g, void* lds) {
  __builtin_amdgcn_global_load_lds(
      (__attribute__((address_space(1))) void*)(uintptr_t)g,
      (__attribute__((address_space(3))) void*)(uint32_t)(uintptr_t)lds,
      16, 0, 0);
}

// ---------------- fp32 -> bf16 convert, grid-stride ----------------
__global__ void cvt_bf16_kernel(const float* __restrict__ in, u16* __restrict__ out, int n4) {
  int stride = gridDim.x * blockDim.x;
  for (int i = blockIdx.x * blockDim.x + threadIdx.x; i < n4; i += stride) {
    float4 v = ((const float4*)in)[i];
    uint32_t lo = (uint32_t)f2bf(v.x) | ((uint32_t)f2bf(v.y) << 16);
    uint32_t hi = (uint32_t)f2bf(v.z) | ((uint32_t)f2bf(v.w) << 16);
    ((uint2*)out)[i] = make_uint2(lo, hi);
  }
}

// ---------------- RoPE cos/sin table ----------------
__global__ void rope_tab_kernel(float* __restrict__ tab) {
  int idx = blockIdx.x * blockDim.x + threadIdx.x;  // NT*64
  int t = idx >> 6, i = idx & 63;
  float inv = expf(-(float)(2 * i) * (9.210340371976184f / 128.f));
  float f = (float)t * inv;
  tab[t * 128 + i] = cosf(f);
  tab[t * 128 + 64 + i] = sinf(f);
}

// ---------------- RoPE apply + head split/transpose (Q and K only) ----------------
__global__ void rope_apply_kernel(const u16* __restrict__ qkv, const float* __restrict__ tab,
                                  u16* __restrict__ Q, u16* __restrict__ K) {
  int idx = blockIdx.x * blockDim.x + threadIdx.x;  // NB*NT*20*64
  int i = idx & 63;
  int rest = idx >> 6;
  int hh = rest % 20;
  int bt = rest / 20;
  int t = bt & (NT - 1);
  int b = bt >> 11;
  const u16* src_row = qkv + (long)bt * NQKV;
  float c = tab[t * 128 + i], s = tab[t * 128 + 64 + i];
  if (hh < NH) {
    const u16* sp = src_row + hh * HD;
    float x0 = bf2f(sp[i]), x1 = bf2f(sp[i + 64]);
    u16* dp = Q + ((long)(b * NH + hh) * NT + t) * HD;
    dp[i] = f2bf((x0 * c - x1 * s) * SCALE2);
    dp[i + 64] = f2bf((x1 * c + x0 * s) * SCALE2);
  } else {
    int kh = hh - NH;
    const u16* sp = src_row + (NH + kh) * HD;
    float x0 = bf2f(sp[i]), x1 = bf2f(sp[i + 64]);
    u16* dp = K + ((long)(b * NKV + kh) * NT + t) * HD;
    dp[i] = f2bf(x0 * c - x1 * s);
    dp[i + 64] = f2bf(x1 * c + x0 * s);
  }
}

// ---------------- V transpose to attn-ready layout ----------------
__global__ void vtrans_kernel(const u16* __restrict__ qkv, u16* __restrict__ Vt) {
  __shared__ u16 tile[64][72];
  const int t0 = (blockIdx.x >> 1) * 64;
  const int d0 = (blockIdx.x & 1) * 64;
  const int bkh = blockIdx.y;                 // b*NKV + kh
  const int tid = threadIdx.x;
  const int tr = tid >> 2;
  const int tc = (tid & 3) * 16;
  const u16* src = qkv + ((long)((bkh >> 2) * NT) + t0 + tr) * NQKV +
                   (NH + NKV) * HD + (bkh & 3) * HD + d0 + tc;
  uint4 v0 = *(const uint4*)(src);
  uint4 v1 = *(const uint4*)(src + 8);
  *(uint4*)&tile[tr][tc] = v0;
  *(uint4*)&tile[tr][tc + 8] = v1;
  __syncthreads();
  const int dr = tid >> 2;
  const int tcc = (tid & 3) * 16;
  uint32_t pk[8];
#pragma unroll
  for (int e = 0; e < 8; ++e) {
    u16 a = tile[tcc + 2 * e][dr];
    u16 bq = tile[tcc + 2 * e + 1][dr];
    pk[e] = (uint32_t)a | ((uint32_t)bq << 16);
  }
  uint32_t tmp;
  tmp = pk[2]; pk[2] = pk[4]; pk[4] = tmp;
  tmp = pk[3]; pk[3] = pk[5]; pk[5] = tmp;
  const int d = d0 + dr;
  const int t = t0 + tcc;
  u16* dst = Vt + (long)bkh * HD * NT + (long)(d >> 1) * (2 * NT) +
             (t >> 6) * 128 + (d & 1) * 64 + (t & 48);
  *(uint4*)(dst) = *(uint4*)&pk[0];
  *(uint4*)(dst + 8) = *(uint4*)&pk[4];
}

// ---------------- GEMM v5: BM=256 x BN=(NREP*32), BK=64, phase-split, A 2-deep / B 3-deep ----------------
// Per K-tile: phA: [stageA(t+1): 4 gl][vmcnt(6|7)][bar][ds ks=0 + MFMA][bar]
//             phB: [stageB(t+2): NREP/2 gl][ds ks=1 + MFMA][bar]
// In-order vmcnt queue at phA wait: [B(t), A(t), B(t+1), A(t+1)] -> allow B(t+1)+A(t+1)
// = NREP/2+4 newest; forces B(t)+A(t) landed while next stages stay in flight.
template <int OUT_BF16, int NREP>
__global__ __launch_bounds__(512, 1) void gemm256_kernel(const u16* __restrict__ A,
                                                         const u16* __restrict__ Bm,
                                                         void* __restrict__ Cm,
                                                         int M, int N, int K) {
  constexpr int BN = NREP * 32;
  __shared__ __align__(16) u16 As[2][256 * 64];   // 32 KB per buf
  __shared__ __align__(16) u16 Bs[3][BN * 64];    // 16/24 KB per buf, 3-deep
  const int tid = threadIdx.x, lane = tid & 63, wid = tid >> 6;
  const int wr = wid >> 1, wc = wid & 1;   // wave: 64 rows x (NREP*16) cols
  const int g = lane >> 4, r = lane & 15;
  // XCD-aware bijective swizzle (T1): grids are 256 blocks = 8 XCDs x 32 contiguous tiles.
  int lin = blockIdx.y * gridDim.x + blockIdx.x;
  const int nwg = gridDim.x * gridDim.y;
  lin = (lin & 7) * (nwg >> 3) + (lin >> 3);
  const int bx = lin % gridDim.x;
  const int by = lin / gridDim.x;
  const long row0 = (long)by * 256;
  const long col0 = (long)bx * BN;
  const int lrow = lane >> 3;   // row within 8-row gload granule
  const int lch = lane & 7;     // 16B granule index within 128B row

  f32x4 acc[4][NREP] = {};

  auto stageA = [&](int bufi, int kt) {
    const int k0 = kt * 64;
    u16* Ad = As[bufi];
#pragma unroll
    for (int ii = 0; ii < 4; ++ii) {
      int rowl = wid * 32 + ii * 8 + lrow;
      const u16* src = A + (row0 + rowl) * (long)K + k0 + ((lch ^ (rowl & 7)) * 8);
      gload16(src, Ad + (wid * 32 + ii * 8) * 64);
    }
  };
  auto stageB = [&](int bufi, int kt) {
    const int k0 = kt * 64;
    u16* Bd = Bs[bufi];
#pragma unroll
    for (int ii = 0; ii < NREP / 2; ++ii) {
      int rowl = wid * (NREP * 4) + ii * 8 + lrow;
      const u16* src = Bm + (col0 + rowl) * (long)K + k0 + ((lch ^ (rowl & 7)) * 8);
      gload16(src, Bd + (wid * (NREP * 4) + ii * 8) * 64);
    }
  };

  const int nt = K / 64;
  stageA(0, 0);
  stageB(0, 0);
  if (nt > 1) stageB(1, 1);
  int abuf = 0;
  int bslot = 0;  // == t % 3
  for (int t = 0; t < nt; ++t) {
    const char* Ab = (const char*)As[abuf];
    const char* Bb = (const char*)Bs[bslot];

    // ---- Phase A: issue A(t+1), counted wait for tile t, compute ks=0 ----
    if (t + 1 < nt) {
      stageA(abuf ^ 1, t + 1);
      __builtin_amdgcn_sched_barrier(0);
      if constexpr (NREP == 4) {
        asm volatile("s_waitcnt vmcnt(6)" ::: "memory");   // allow B(t+1)2 + A(t+1)4
      } else {
        asm volatile("s_waitcnt vmcnt(7)" ::: "memory");   // allow B(t+1)3 + A(t+1)4
      }
    } else {
      __builtin_amdgcn_sched_barrier(0);
      asm volatile("s_waitcnt vmcnt(0)" ::: "memory");
    }
    __builtin_amdgcn_sched_barrier(0);
    __builtin_amdgcn_s_barrier();
    __builtin_amdgcn_sched_barrier(0);
    {
      bf16x8 af[4], bfv[NREP];
#pragma unroll
      for (int mi = 0; mi < 4; ++mi) {
        int row = wr * 64 + mi * 16 + r;
        af[mi] = *(const bf16x8*)(Ab + row * 128 + ((g ^ (row & 7)) * 16));
      }
#pragma unroll
      for (int ni = 0; ni < NREP; ++ni) {
        int row = wc * (NREP * 16) + ni * 16 + r;
        bfv[ni] = *(const bf16x8*)(Bb + row * 128 + ((g ^ (row & 7)) * 16));
      }
      __builtin_amdgcn_s_setprio(1);
#pragma unroll
      for (int mi = 0; mi < 4; ++mi)
#pragma unroll
        for (int ni = 0; ni < NREP; ++ni)
          acc[mi][ni] = __builtin_amdgcn_mfma_f32_16x16x32_bf16(af[mi], bfv[ni], acc[mi][ni], 0, 0, 0);
      __builtin_amdgcn_s_setprio(0);
    }
    __builtin_amdgcn_sched_barrier(0);
    __builtin_amdgcn_s_barrier();
    __builtin_amdgcn_sched_barrier(0);

    // ---- Phase B: issue B(t+2) two tiles ahead, compute ks=1 ----
    if (t + 2 < nt) {
      int s2 = bslot + 2; if (s2 >= 3) s2 -= 3;   // (t+2) % 3
      stageB(s2, t + 2);
    }
    __builtin_amdgcn_sched_barrier(0);
    {
      bf16x8 af[4], bfv[NREP];
#pragma unroll
      for (int mi = 0; mi < 4; ++mi) {
        int row = wr * 64 + mi * 16 + r;
        af[mi] = *(const bf16x8*)(Ab + row * 128 + (((4 + g) ^ (row & 7)) * 16));
      }
#pragma unroll
      for (int ni = 0; ni < NREP; ++ni) {
        int row = wc * (NREP * 16) + ni * 16 + r;
        bfv[ni] = *(const bf16x8*)(Bb + row * 128 + (((4 + g) ^ (row & 7)) * 16));
      }
      __builtin_amdgcn_s_setprio(1);
#pragma unroll
      for (int mi = 0; mi < 4; ++mi)
#pragma unroll
        for (int ni = 0; ni < NREP; ++ni)
          acc[mi][ni] = __builtin_amdgcn_mfma_f32_16x16x32_bf16(af[mi], bfv[ni], acc[mi][ni], 0, 0, 0);
      __builtin_amdgcn_s_setprio(0);
    }
    __builtin_amdgcn_sched_barrier(0);
    __builtin_amdgcn_s_barrier();
    __builtin_amdgcn_sched_barrier(0);
    abuf ^= 1;
    if (++bslot >= 3) bslot = 0;
  }

#pragma unroll
  for (int mi = 0; mi < 4; ++mi)
#pragma unroll
    for (int ni = 0; ni < NREP; ++ni)
#pragma unroll
      for (int j = 0; j < 4; ++j) {
        long rr = row0 + wr * 64 + mi * 16 + g * 4 + j;
        long cc = col0 + wc * (NREP * 16) + ni * 16 + r;
        float v = acc[mi][ni][j];
        if (OUT_BF16) ((u16*)Cm)[rr * N + cc] = f2bf(v);
        else          ((float*)Cm)[rr * N + cc] = v;
      }
}

// ---------------- Flash attention v10 (round-15 best): 32x32 MFMA, register P, paired blocks ----------------
__global__ __launch_bounds__(256, 2) void attn_kernel(const u16* __restrict__ Qg,
                                                      const u16* __restrict__ Kg,
                                                      const u16* __restrict__ Vtg,
                                                      const float* __restrict__ amask,
                                                      u16* __restrict__ Y) {
  __shared__ __align__(16) u16 Ks[2][64 * 128];  // [kv][d], granule-swizzled ^(kv&15)
  __shared__ __align__(16) u16 Vs[2][64 * 128];  // [drow][256B], granule-swizzled ^(drow&15)
  const int tid = threadIdx.x, lane = tid & 63, wid = tid >> 6;
  const int ql = lane & 31, hi = lane >> 5;
  const int id = blockIdx.x;
  const int h = id & 15;
  const int xp = (id >> 4) & 7;
  const int b = (id >> 7) & 1;
  const int half = id >> 8;
  const int qt = half ? 15 - xp : xp;
  const int q0 = qt * 128;
  const int kh = h >> 2;

  const u16* Kbh = Kg + (long)(b * NKV + kh) * NT * HD;
  const u16* Vtbh = Vtg + (long)(b * NKV + kh) * HD * NT;
  const u16* Qbh = Qg + (long)(b * NH + h) * NT * HD;
  const float* am_b = amask + b * NT;

  const int total = 2 * qt + 2;  // causal KV-64 tiles for this q-tile

  const int srow = lane >> 4;    // 4 rows (256B each) per gload
  const int schunk = lane & 15;  // 16B granule within row
  auto stageK = [&](u16* dst, int kv0) {
#pragma unroll
    for (int ii = 0; ii < 4; ++ii) {
      int kvl = wid * 16 + ii * 4 + srow;
      const u16* src = Kbh + (long)(kv0 + kvl) * HD + ((schunk ^ (kvl & 15)) * 8);
      gload16(src, dst + (wid * 16 + ii * 4) * 128);
    }
  };
  auto stageV = [&](u16* dst, int kv0) {
    const u16* vb = Vtbh + (kv0 >> 6) * 128;
#pragma unroll
    for (int ii = 0; ii < 4; ++ii) {
      int R = wid * 16 + ii * 4 + srow;
      const u16* src = vb + (long)R * (2 * NT) + ((schunk ^ (R & 15)) * 8);
      gload16(src, dst + (wid * 16 + ii * 4) * 128);
    }
  };

  bf16x8 qf[8];
  {
    const u16* Qrow = Qbh + (long)(q0 + wid * 32 + ql) * HD;
#pragma unroll
    for (int ks = 0; ks < 8; ++ks)
      qf[ks] = *(const bf16x8*)(Qrow + ks * 16 + 8 * hi);
  }

  // ---- prologue ----
  stageK(Ks[0], 0);
  stageV(Vs[0], 0);
  __syncthreads();

  float m = -INFINITY;
  f32x4 lacc = {};
  f32x16 o[4] = {};
  int buf = 0;
  const int qi = q0 + wid * 32 + ql;

  for (int i = 0; i < total; ++i) {
    const int kv0 = i * 64;

    if (i + 1 < total) {
      stageK(Ks[buf ^ 1], (i + 1) * 64);
      stageV(Vs[buf ^ 1], (i + 1) * 64);
    }

    const char* Ksb = (const char*)Ks[buf];
    const char* Vsb = (const char*)Vs[buf];

    // ---- S^T = mfma(K, Q): 4 independent chains of 4 (split accumulators) ----
    f32x16 s0a = {}, s0b = {}, s1a = {}, s1b = {};
    __builtin_amdgcn_s_setprio(1);
#pragma unroll
    for (int ks = 0; ks < 4; ++ks) {
      bf16x8 kf0 = *(const bf16x8*)(Ksb + ql * 256 + (((2 * ks + hi) ^ (ql & 15)) * 16));
      bf16x8 kf1 = *(const bf16x8*)(Ksb + (32 + ql) * 256 + (((2 * ks + hi) ^ (ql & 15)) * 16));
      s0a = __builtin_amdgcn_mfma_f32_32x32x16_bf16(kf0, qf[ks], s0a, 0, 0, 0);
      s1a = __builtin_amdgcn_mfma_f32_32x32x16_bf16(kf1, qf[ks], s1a, 0, 0, 0);
    }
#pragma unroll
    for (int ks = 4; ks < 8; ++ks) {
      bf16x8 kf0 = *(const bf16x8*)(Ksb + ql * 256 + (((2 * ks + hi) ^ (ql & 15)) * 16));
      bf16x8 kf1 = *(const bf16x8*)(Ksb + (32 + ql) * 256 + (((2 * ks + hi) ^ (ql & 15)) * 16));
      s0b = __builtin_amdgcn_mfma_f32_32x32x16_bf16(kf0, qf[ks], s0b, 0, 0, 0);
      s1b = __builtin_amdgcn_mfma_f32_32x32x16_bf16(kf1, qf[ks], s1b, 0, 0, 0);
    }
    __builtin_amdgcn_s_setprio(0);
    f32x16 s0 = s0a + s0b;
    f32x16 s1 = s1a + s1b;

    // ---- causal mask (tiles overlapping the diagonal zone) ----
    if (i >= 2 * qt) {
#pragma unroll
      for (int reg = 0; reg < 16; ++reg) {
        int kvl = (reg & 3) + 8 * (reg >> 2) + 4 * hi;
        if (kv0 + kvl > qi) s0[reg] = -INFINITY;
        if (kv0 + 32 + kvl > qi) s1[reg] = -INFINITY;
      }
    }

    // ---- defer-max: explicit binary tree (depth 5), wave-uniform check, no shfl ----
    float t16[16];
#pragma unroll
    for (int reg = 0; reg < 16; ++reg) t16[reg] = fmaxf(s0[reg], s1[reg]);
    float t8[8];
#pragma unroll
    for (int reg = 0; reg < 8; ++reg) t8[reg] = fmaxf(t16[reg], t16[reg + 8]);
    float t4[4];
#pragma unroll
    for (int reg = 0; reg < 4; ++reg) t4[reg] = fmaxf(t8[reg], t8[reg + 4]);
    float mxl = fmaxf(fmaxf(t4[0], t4[1]), fmaxf(t4[2], t4[3]));
    if (!__all(mxl <= m + 8.f)) {
      float mx = fmaxf(mxl, __shfl_xor(mxl, 32));
      float mnew = fmaxf(m, mx);
      float alpha = exp2f(m - mnew);
      m = mnew;
      lacc *= alpha;
#pragma unroll
      for (int dblk = 0; dblk < 4; ++dblk) o[dblk] *= alpha;
    }

    // ---- P = exp2(S - m) * mask (in place) ----
    float4 am0[4], am1[4];
#pragma unroll
    for (int uu = 0; uu < 4; ++uu) {
      am0[uu] = *(const float4*)(am_b + kv0 + 8 * uu + 4 * hi);
      am1[uu] = *(const float4*)(am_b + kv0 + 32 + 8 * uu + 4 * hi);
    }
#pragma unroll
    for (int reg = 0; reg < 16; ++reg) {
      float p0 = exp2f(s0[reg] - m) * (&am0[reg >> 2].x)[reg & 3];
      float p1 = exp2f(s1[reg] - m) * (&am1[reg >> 2].x)[reg & 3];
      s0[reg] = p0; s1[reg] = p1;
      lacc[reg & 3] += p0 + p1;
    }

    // ---- pack P fragments from own regs (sigma-matched, no LDS) ----
    bf16x8 pb[4];
#pragma unroll
    for (int ks = 0; ks < 4; ++ks) {
      union { __bf16 hh[8]; bf16x8 v; } pk;
      const int base = 8 * (ks & 1);
#pragma unroll
      for (int j = 0; j < 8; ++j)
        pk.hh[j] = (__bf16)((ks >= 2) ? s1[base + j] : s0[base + j]);
      pb[ks] = pk.v;
    }

    // ---- O^T += mfma(V^T, P): A row d = 32*dblk + ql (4 independent chains) ----
    __builtin_amdgcn_s_setprio(1);
#pragma unroll
    for (int ks = 0; ks < 4; ++ks) {
#pragma unroll
      for (int dblk = 0; dblk < 4; ++dblk) {
        int drow = dblk * 16 + (ql >> 1);
        int gr = ((ql & 1) * 8 + 2 * ks + hi) ^ (drow & 15);
        bf16x8 va = *(const bf16x8*)(Vsb + drow * 256 + gr * 16);
        o[dblk] = __builtin_amdgcn_mfma_f32_32x32x16_bf16(va, pb[ks], o[dblk], 0, 0, 0);
      }
    }
    __builtin_amdgcn_s_setprio(0);

    __syncthreads();
    buf ^= 1;
  }

  // ---- epilogue: reduce l once, write Y ----
  {
    float l = (lacc[0] + lacc[1]) + (lacc[2] + lacc[3]);
    l += __shfl_xor(l, 32);
    float invl = 1.f / l;
    u16* Yrow = Y + ((long)b * NT + qi) * NC + h * HD;
#pragma unroll
    for (int dblk = 0; dblk < 4; ++dblk)
#pragma unroll
      for (int uu = 0; uu < 4; ++uu) {
        int d = dblk * 32 + 8 * uu + 4 * hi;
        int r0 = 4 * uu;
        *(uint2*)(Yrow + d) = make_uint2(
            packbf2(o[dblk][r0] * invl, o[dblk][r0 + 1] * invl),
            packbf2(o[dblk][r0 + 2] * invl, o[dblk][r0 + 3] * invl));
      }
  }
}

extern "C" void kernel_launch(void* const* d_in, const int* in_sizes, int n_in,
                              void* d_out, int out_size, void* d_ws, size_t ws_size,
                              hipStream_t stream) {
  const float* x = (const float*)d_in[0];
  const float* amask = (const float*)d_in[1];
  const float* w_qkv = (const float*)d_in[2];
  const float* w_proj = (const float*)d_in[3];

  const long MT = (long)NB * NT;  // 4096
  char* ws = (char*)d_ws;
  size_t off = 0;
  auto carve = [&](size_t bytes) -> char* {
    char* p = ws + off;
    off += (bytes + 255) & ~(size_t)255;
    return p;
  };
  u16* xb   = (u16*)carve((size_t)MT * NC * 2);       // A for gemm1; later Q
  u16* wqb  = (u16*)carve((size_t)NQKV * NC * 2);     // B for gemm1; later K + Vt
  u16* wpb  = (u16*)carve((size_t)NC * NC * 2);       // B for gemm2
  u16* qkvb = (u16*)carve((size_t)MT * NQKV * 2);     // C of gemm1; later Y
  float* tab = (float*)carve((size_t)NT * 128 * 4);

  u16* Qb = xb;
  u16* Kb = wqb;
  u16* Vtb = wqb + (size_t)NB * NKV * NT * HD;
  u16* Yb = qkvb;

  {
    int n4 = (int)(MT * NC / 4);
    cvt_bf16_kernel<<<dim3(2048), dim3(256), 0, stream>>>(x, xb, n4);
    n4 = (int)((long)NQKV * NC / 4);
    cvt_bf16_kernel<<<dim3(2048), dim3(256), 0, stream>>>(w_qkv, wqb, n4);
    n4 = (int)((long)NC * NC / 4);
    cvt_bf16_kernel<<<dim3(2048), dim3(256), 0, stream>>>(w_proj, wpb, n4);
  }
  rope_tab_kernel<<<dim3(NT * 64 / 256), dim3(256), 0, stream>>>(tab);
  gemm256_kernel<1, 6><<<dim3(NQKV / 192, MT / 256), dim3(512), 0, stream>>>(xb, wqb, qkvb, (int)MT, NQKV, NC);
  rope_apply_kernel<<<dim3(NB * NT * 20 * 64 / 256), dim3(256), 0, stream>>>(qkvb, tab, Qb, Kb);
  vtrans_kernel<<<dim3(NT / 64 * 2, NB * NKV), dim3(256), 0, stream>>>(qkvb, Vtb);
  attn_kernel<<<dim3(512), dim3(256), 0, stream>>>(Qb, Kb, Vtb, amask, Yb);
  gemm256_kernel<0, 4><<<dim3(NC / 128, MT / 256), dim3(512), 0, stream>>>(Yb, wpb, d_out, (int)MT, NC, NC);
}

// Round 21
// 192.685 us; speedup vs baseline: 1.1241x; 1.0120x over previous
//
#include <hip/hip_runtime.h>
#include <hip/hip_bf16.h>
#include <stdint.h>

typedef unsigned short u16;
typedef __attribute__((ext_vector_type(4))) float f32x4;
typedef __attribute__((ext_vector_type(16))) float f32x16;
typedef __attribute__((ext_vector_type(8))) __bf16 bf16x8;

#define NB 2
#define NT 2048
#define NC 2048
#define NH 16
#define NKV 4
#define HD 128
#define NQKV 3072
#define SCALE2 0.12751739f  // (1/sqrt(128)) * log2(e)

__device__ __forceinline__ u16 f2bf(float f) {
  union { float f; uint32_t u; } c; c.f = f;
  uint32_t u = c.u + 0x7fffu + ((c.u >> 16) & 1u);
  return (u16)(u >> 16);
}
__device__ __forceinline__ float bf2f(u16 h) {
  union { uint32_t u; float f; } c; c.u = ((uint32_t)h) << 16;
  return c.f;
}
__device__ __forceinline__ uint32_t packbf2(float a, float b) {
  return (uint32_t)f2bf(a) | ((uint32_t)f2bf(b) << 16);
}

// global -> LDS async copy, 16B per lane. LDS dest = wave-uniform base + lane*16.
__device__ __forceinline__ void gload16(const void* g, void* lds) {
  __builtin_amdgcn_global_load_lds(
      (__attribute__((address_space(1))) void*)(uintptr_t)g,
      (__attribute__((address_space(3))) void*)(uint32_t)(uintptr_t)lds,
      16, 0, 0);
}

// ---------------- fp32 -> bf16 convert: all three tensors in ONE launch ----------------
__global__ void cvt3_kernel(const float* __restrict__ a, u16* __restrict__ ao, int na4,
                            const float* __restrict__ b, u16* __restrict__ bo, int nb4,
                            const float* __restrict__ c, u16* __restrict__ co, int nc4) {
  const int stride = gridDim.x * blockDim.x;
  const int total = na4 + nb4 + nc4;
  for (int i = blockIdx.x * blockDim.x + threadIdx.x; i < total; i += stride) {
    const float* in; u16* out; int idx;
    if (i < na4) { in = a; out = ao; idx = i; }
    else if (i < na4 + nb4) { in = b; out = bo; idx = i - na4; }
    else { in = c; out = co; idx = i - na4 - nb4; }
    float4 v = ((const float4*)in)[idx];
    uint32_t lo = (uint32_t)f2bf(v.x) | ((uint32_t)f2bf(v.y) << 16);
    uint32_t hi = (uint32_t)f2bf(v.z) | ((uint32_t)f2bf(v.w) << 16);
    ((uint2*)out)[idx] = make_uint2(lo, hi);
  }
}

// ---------------- RoPE cos/sin table ----------------
__global__ void rope_tab_kernel(float* __restrict__ tab) {
  int idx = blockIdx.x * blockDim.x + threadIdx.x;  // NT*64
  int t = idx >> 6, i = idx & 63;
  float inv = expf(-(float)(2 * i) * (9.210340371976184f / 128.f));
  float f = (float)t * inv;
  tab[t * 128 + i] = cosf(f);
  tab[t * 128 + 64 + i] = sinf(f);
}

// ---------------- RoPE apply + head split/transpose (Q and K only) ----------------
__global__ void rope_apply_kernel(const u16* __restrict__ qkv, const float* __restrict__ tab,
                                  u16* __restrict__ Q, u16* __restrict__ K) {
  int idx = blockIdx.x * blockDim.x + threadIdx.x;  // NB*NT*20*64
  int i = idx & 63;
  int rest = idx >> 6;
  int hh = rest % 20;
  int bt = rest / 20;
  int t = bt & (NT - 1);
  int b = bt >> 11;
  const u16* src_row = qkv + (long)bt * NQKV;
  float c = tab[t * 128 + i], s = tab[t * 128 + 64 + i];
  if (hh < NH) {
    const u16* sp = src_row + hh * HD;
    float x0 = bf2f(sp[i]), x1 = bf2f(sp[i + 64]);
    u16* dp = Q + ((long)(b * NH + hh) * NT + t) * HD;
    dp[i] = f2bf((x0 * c - x1 * s) * SCALE2);
    dp[i + 64] = f2bf((x1 * c + x0 * s) * SCALE2);
  } else {
    int kh = hh - NH;
    const u16* sp = src_row + (NH + kh) * HD;
    float x0 = bf2f(sp[i]), x1 = bf2f(sp[i + 64]);
    u16* dp = K + ((long)(b * NKV + kh) * NT + t) * HD;
    dp[i] = f2bf(x0 * c - x1 * s);
    dp[i + 64] = f2bf(x1 * c + x0 * s);
  }
}

// ---------------- V transpose to attn-ready layout ----------------
__global__ void vtrans_kernel(const u16* __restrict__ qkv, u16* __restrict__ Vt) {
  __shared__ u16 tile[64][72];
  const int t0 = (blockIdx.x >> 1) * 64;
  const int d0 = (blockIdx.x & 1) * 64;
  const int bkh = blockIdx.y;                 // b*NKV + kh
  const int tid = threadIdx.x;
  const int tr = tid >> 2;
  const int tc = (tid & 3) * 16;
  const u16* src = qkv + ((long)((bkh >> 2) * NT) + t0 + tr) * NQKV +
                   (NH + NKV) * HD + (bkh & 3) * HD + d0 + tc;
  uint4 v0 = *(const uint4*)(src);
  uint4 v1 = *(const uint4*)(src + 8);
  *(uint4*)&tile[tr][tc] = v0;
  *(uint4*)&tile[tr][tc + 8] = v1;
  __syncthreads();
  const int dr = tid >> 2;
  const int tcc = (tid & 3) * 16;
  uint32_t pk[8];
#pragma unroll
  for (int e = 0; e < 8; ++e) {
    u16 a = tile[tcc + 2 * e][dr];
    u16 bq = tile[tcc + 2 * e + 1][dr];
    pk[e] = (uint32_t)a | ((uint32_t)bq << 16);
  }
  uint32_t tmp;
  tmp = pk[2]; pk[2] = pk[4]; pk[4] = tmp;
  tmp = pk[3]; pk[3] = pk[5]; pk[5] = tmp;
  const int d = d0 + dr;
  const int t = t0 + tcc;
  u16* dst = Vt + (long)bkh * HD * NT + (long)(d >> 1) * (2 * NT) +
             (t >> 6) * 128 + (d & 1) * 64 + (t & 48);
  *(uint4*)(dst) = *(uint4*)&pk[0];
  *(uint4*)(dst + 8) = *(uint4*)&pk[4];
}

// ---------------- GEMM v6: BM=256 x BN=(NREP*32), BK=64, phase-split, A 2-deep / B 3-deep ----------------
// Per K-tile: phA: [stageA(t+1): 4 gl][vmcnt(6|7)][bar][ds ks=0 + MFMA][bar]
//             phB: [stageB(t+2): NREP/2 gl][ds ks=1 + MFMA][bar]
// XCD mapping: both grids are 16x16; each XCD owns a 4(by) x 8(bx) rectangle
// (perimeter-minimal L2 footprint: 4 A-panels + 8 B-panels vs 2+16 for strips).
template <int OUT_BF16, int NREP>
__global__ __launch_bounds__(512, 1) void gemm256_kernel(const u16* __restrict__ A,
                                                         const u16* __restrict__ Bm,
                                                         void* __restrict__ Cm,
                                                         int M, int N, int K) {
  constexpr int BN = NREP * 32;
  __shared__ __align__(16) u16 As[2][256 * 64];   // 32 KB per buf
  __shared__ __align__(16) u16 Bs[3][BN * 64];    // 16/24 KB per buf, 3-deep
  const int tid = threadIdx.x, lane = tid & 63, wid = tid >> 6;
  const int wr = wid >> 1, wc = wid & 1;   // wave: 64 rows x (NREP*16) cols
  const int g = lane >> 4, r = lane & 15;
  // 4x8 rectangle per XCD (grids are exactly 16x16 = 256 blocks, 8 XCDs x 32 blocks)
  const int lin = blockIdx.y * gridDim.x + blockIdx.x;
  const int xcd = lin & 7;
  const int j = lin >> 3;                  // 0..31 within rectangle
  const int by = (xcd >> 1) * 4 + (j >> 3);
  const int bx = (xcd & 1) * 8 + (j & 7);
  const long row0 = (long)by * 256;
  const long col0 = (long)bx * BN;
  const int lrow = lane >> 3;   // row within 8-row gload granule
  const int lch = lane & 7;     // 16B granule index within 128B row

  f32x4 acc[4][NREP] = {};

  auto stageA = [&](int bufi, int kt) {
    const int k0 = kt * 64;
    u16* Ad = As[bufi];
#pragma unroll
    for (int ii = 0; ii < 4; ++ii) {
      int rowl = wid * 32 + ii * 8 + lrow;
      const u16* src = A + (row0 + rowl) * (long)K + k0 + ((lch ^ (rowl & 7)) * 8);
      gload16(src, Ad + (wid * 32 + ii * 8) * 64);
    }
  };
  auto stageB = [&](int bufi, int kt) {
    const int k0 = kt * 64;
    u16* Bd = Bs[bufi];
#pragma unroll
    for (int ii = 0; ii < NREP / 2; ++ii) {
      int rowl = wid * (NREP * 4) + ii * 8 + lrow;
      const u16* src = Bm + (col0 + rowl) * (long)K + k0 + ((lch ^ (rowl & 7)) * 8);
      gload16(src, Bd + (wid * (NREP * 4) + ii * 8) * 64);
    }
  };

  const int nt = K / 64;
  stageA(0, 0);
  stageB(0, 0);
  if (nt > 1) stageB(1, 1);
  int abuf = 0;
  int bslot = 0;  // == t % 3
  for (int t = 0; t < nt; ++t) {
    const char* Ab = (const char*)As[abuf];
    const char* Bb = (const char*)Bs[bslot];

    // ---- Phase A: issue A(t+1), counted wait for tile t, compute ks=0 ----
    if (t + 1 < nt) {
      stageA(abuf ^ 1, t + 1);
      __builtin_amdgcn_sched_barrier(0);
      if constexpr (NREP == 4) {
        asm volatile("s_waitcnt vmcnt(6)" ::: "memory");   // allow B(t+1)2 + A(t+1)4
      } else {
        asm volatile("s_waitcnt vmcnt(7)" ::: "memory");   // allow B(t+1)3 + A(t+1)4
      }
    } else {
      __builtin_amdgcn_sched_barrier(0);
      asm volatile("s_waitcnt vmcnt(0)" ::: "memory");
    }
    __builtin_amdgcn_sched_barrier(0);
    __builtin_amdgcn_s_barrier();
    __builtin_amdgcn_sched_barrier(0);
    {
      bf16x8 af[4], bfv[NREP];
#pragma unroll
      for (int mi = 0; mi < 4; ++mi) {
        int row = wr * 64 + mi * 16 + r;
        af[mi] = *(const bf16x8*)(Ab + row * 128 + ((g ^ (row & 7)) * 16));
      }
#pragma unroll
      for (int ni = 0; ni < NREP; ++ni) {
        int row = wc * (NREP * 16) + ni * 16 + r;
        bfv[ni] = *(const bf16x8*)(Bb + row * 128 + ((g ^ (row & 7)) * 16));
      }
      __builtin_amdgcn_s_setprio(1);
#pragma unroll
      for (int mi = 0; mi < 4; ++mi)
#pragma unroll
        for (int ni = 0; ni < NREP; ++ni)
          acc[mi][ni] = __builtin_amdgcn_mfma_f32_16x16x32_bf16(af[mi], bfv[ni], acc[mi][ni], 0, 0, 0);
      __builtin_amdgcn_s_setprio(0);
    }
    __builtin_amdgcn_sched_barrier(0);
    __builtin_amdgcn_s_barrier();
    __builtin_amdgcn_sched_barrier(0);

    // ---- Phase B: issue B(t+2) two tiles ahead, compute ks=1 ----
    if (t + 2 < nt) {
      int s2 = bslot + 2; if (s2 >= 3) s2 -= 3;   // (t+2) % 3
      stageB(s2, t + 2);
    }
    __builtin_amdgcn_sched_barrier(0);
    {
      bf16x8 af[4], bfv[NREP];
#pragma unroll
      for (int mi = 0; mi < 4; ++mi) {
        int row = wr * 64 + mi * 16 + r;
        af[mi] = *(const bf16x8*)(Ab + row * 128 + (((4 + g) ^ (row & 7)) * 16));
      }
#pragma unroll
      for (int ni = 0; ni < NREP; ++ni) {
        int row = wc * (NREP * 16) + ni * 16 + r;
        bfv[ni] = *(const bf16x8*)(Bb + row * 128 + (((4 + g) ^ (row & 7)) * 16));
      }
      __builtin_amdgcn_s_setprio(1);
#pragma unroll
      for (int mi = 0; mi < 4; ++mi)
#pragma unroll
        for (int ni = 0; ni < NREP; ++ni)
          acc[mi][ni] = __builtin_amdgcn_mfma_f32_16x16x32_bf16(af[mi], bfv[ni], acc[mi][ni], 0, 0, 0);
      __builtin_amdgcn_s_setprio(0);
    }
    __builtin_amdgcn_sched_barrier(0);
    __builtin_amdgcn_s_barrier();
    __builtin_amdgcn_sched_barrier(0);
    abuf ^= 1;
    if (++bslot >= 3) bslot = 0;
  }

#pragma unroll
  for (int mi = 0; mi < 4; ++mi)
#pragma unroll
    for (int ni = 0; ni < NREP; ++ni)
#pragma unroll
      for (int j2 = 0; j2 < 4; ++j2) {
        long rr = row0 + wr * 64 + mi * 16 + g * 4 + j2;
        long cc = col0 + wc * (NREP * 16) + ni * 16 + r;
        float v = acc[mi][ni][j2];
        if (OUT_BF16) ((u16*)Cm)[rr * N + cc] = f2bf(v);
        else          ((float*)Cm)[rr * N + cc] = v;
      }
}

// ---------------- Flash attention v10 (round-15 best): 32x32 MFMA, register P, paired blocks ----------------
__global__ __launch_bounds__(256, 2) void attn_kernel(const u16* __restrict__ Qg,
                                                      const u16* __restrict__ Kg,
                                                      const u16* __restrict__ Vtg,
                                                      const float* __restrict__ amask,
                                                      u16* __restrict__ Y) {
  __shared__ __align__(16) u16 Ks[2][64 * 128];  // [kv][d], granule-swizzled ^(kv&15)
  __shared__ __align__(16) u16 Vs[2][64 * 128];  // [drow][256B], granule-swizzled ^(drow&15)
  const int tid = threadIdx.x, lane = tid & 63, wid = tid >> 6;
  const int ql = lane & 31, hi = lane >> 5;
  const int id = blockIdx.x;
  const int h = id & 15;
  const int xp = (id >> 4) & 7;
  const int b = (id >> 7) & 1;
  const int half = id >> 8;
  const int qt = half ? 15 - xp : xp;
  const int q0 = qt * 128;
  const int kh = h >> 2;

  const u16* Kbh = Kg + (long)(b * NKV + kh) * NT * HD;
  const u16* Vtbh = Vtg + (long)(b * NKV + kh) * HD * NT;
  const u16* Qbh = Qg + (long)(b * NH + h) * NT * HD;
  const float* am_b = amask + b * NT;

  const int total = 2 * qt + 2;  // causal KV-64 tiles for this q-tile

  const int srow = lane >> 4;    // 4 rows (256B each) per gload
  const int schunk = lane & 15;  // 16B granule within row
  auto stageK = [&](u16* dst, int kv0) {
#pragma unroll
    for (int ii = 0; ii < 4; ++ii) {
      int kvl = wid * 16 + ii * 4 + srow;
      const u16* src = Kbh + (long)(kv0 + kvl) * HD + ((schunk ^ (kvl & 15)) * 8);
      gload16(src, dst + (wid * 16 + ii * 4) * 128);
    }
  };
  auto stageV = [&](u16* dst, int kv0) {
    const u16* vb = Vtbh + (kv0 >> 6) * 128;
#pragma unroll
    for (int ii = 0; ii < 4; ++ii) {
      int R = wid * 16 + ii * 4 + srow;
      const u16* src = vb + (long)R * (2 * NT) + ((schunk ^ (R & 15)) * 8);
      gload16(src, dst + (wid * 16 + ii * 4) * 128);
    }
  };

  bf16x8 qf[8];
  {
    const u16* Qrow = Qbh + (long)(q0 + wid * 32 + ql) * HD;
#pragma unroll
    for (int ks = 0; ks < 8; ++ks)
      qf[ks] = *(const bf16x8*)(Qrow + ks * 16 + 8 * hi);
  }

  // ---- prologue ----
  stageK(Ks[0], 0);
  stageV(Vs[0], 0);
  __syncthreads();

  float m = -INFINITY;
  f32x4 lacc = {};
  f32x16 o[4] = {};
  int buf = 0;
  const int qi = q0 + wid * 32 + ql;

  for (int i = 0; i < total; ++i) {
    const int kv0 = i * 64;

    if (i + 1 < total) {
      stageK(Ks[buf ^ 1], (i + 1) * 64);
      stageV(Vs[buf ^ 1], (i + 1) * 64);
    }

    const char* Ksb = (const char*)Ks[buf];
    const char* Vsb = (const char*)Vs[buf];

    // ---- S^T = mfma(K, Q): 4 independent chains of 4 (split accumulators) ----
    f32x16 s0a = {}, s0b = {}, s1a = {}, s1b = {};
    __builtin_amdgcn_s_setprio(1);
#pragma unroll
    for (int ks = 0; ks < 4; ++ks) {
      bf16x8 kf0 = *(const bf16x8*)(Ksb + ql * 256 + (((2 * ks + hi) ^ (ql & 15)) * 16));
      bf16x8 kf1 = *(const bf16x8*)(Ksb + (32 + ql) * 256 + (((2 * ks + hi) ^ (ql & 15)) * 16));
      s0a = __builtin_amdgcn_mfma_f32_32x32x16_bf16(kf0, qf[ks], s0a, 0, 0, 0);
      s1a = __builtin_amdgcn_mfma_f32_32x32x16_bf16(kf1, qf[ks], s1a, 0, 0, 0);
    }
#pragma unroll
    for (int ks = 4; ks < 8; ++ks) {
      bf16x8 kf0 = *(const bf16x8*)(Ksb + ql * 256 + (((2 * ks + hi) ^ (ql & 15)) * 16));
      bf16x8 kf1 = *(const bf16x8*)(Ksb + (32 + ql) * 256 + (((2 * ks + hi) ^ (ql & 15)) * 16));
      s0b = __builtin_amdgcn_mfma_f32_32x32x16_bf16(kf0, qf[ks], s0b, 0, 0, 0);
      s1b = __builtin_amdgcn_mfma_f32_32x32x16_bf16(kf1, qf[ks], s1b, 0, 0, 0);
    }
    __builtin_amdgcn_s_setprio(0);
    f32x16 s0 = s0a + s0b;
    f32x16 s1 = s1a + s1b;

    // ---- causal mask (tiles overlapping the diagonal zone) ----
    if (i >= 2 * qt) {
#pragma unroll
      for (int reg = 0; reg < 16; ++reg) {
        int kvl = (reg & 3) + 8 * (reg >> 2) + 4 * hi;
        if (kv0 + kvl > qi) s0[reg] = -INFINITY;
        if (kv0 + 32 + kvl > qi) s1[reg] = -INFINITY;
      }
    }

    // ---- defer-max: explicit binary tree (depth 5), wave-uniform check, no shfl ----
    float t16[16];
#pragma unroll
    for (int reg = 0; reg < 16; ++reg) t16[reg] = fmaxf(s0[reg], s1[reg]);
    float t8[8];
#pragma unroll
    for (int reg = 0; reg < 8; ++reg) t8[reg] = fmaxf(t16[reg], t16[reg + 8]);
    float t4[4];
#pragma unroll
    for (int reg = 0; reg < 4; ++reg) t4[reg] = fmaxf(t8[reg], t8[reg + 4]);
    float mxl = fmaxf(fmaxf(t4[0], t4[1]), fmaxf(t4[2], t4[3]));
    if (!__all(mxl <= m + 8.f)) {
      float mx = fmaxf(mxl, __shfl_xor(mxl, 32));
      float mnew = fmaxf(m, mx);
      float alpha = exp2f(m - mnew);
      m = mnew;
      lacc *= alpha;
#pragma unroll
      for (int dblk = 0; dblk < 4; ++dblk) o[dblk] *= alpha;
    }

    // ---- P = exp2(S - m) * mask (in place) ----
    float4 am0[4], am1[4];
#pragma unroll
    for (int uu = 0; uu < 4; ++uu) {
      am0[uu] = *(const float4*)(am_b + kv0 + 8 * uu + 4 * hi);
      am1[uu] = *(const float4*)(am_b + kv0 + 32 + 8 * uu + 4 * hi);
    }
#pragma unroll
    for (int reg = 0; reg < 16; ++reg) {
      float p0 = exp2f(s0[reg] - m) * (&am0[reg >> 2].x)[reg & 3];
      float p1 = exp2f(s1[reg] - m) * (&am1[reg >> 2].x)[reg & 3];
      s0[reg] = p0; s1[reg] = p1;
      lacc[reg & 3] += p0 + p1;
    }

    // ---- pack P fragments from own regs (sigma-matched, no LDS) ----
    bf16x8 pb[4];
#pragma unroll
    for (int ks = 0; ks < 4; ++ks) {
      union { __bf16 hh[8]; bf16x8 v; } pk;
      const int base = 8 * (ks & 1);
#pragma unroll
      for (int j = 0; j < 8; ++j)
        pk.hh[j] = (__bf16)((ks >= 2) ? s1[base + j] : s0[base + j]);
      pb[ks] = pk.v;
    }

    // ---- O^T += mfma(V^T, P): A row d = 32*dblk + ql (4 independent chains) ----
    __builtin_amdgcn_s_setprio(1);
#pragma unroll
    for (int ks = 0; ks < 4; ++ks) {
#pragma unroll
      for (int dblk = 0; dblk < 4; ++dblk) {
        int drow = dblk * 16 + (ql >> 1);
        int gr = ((ql & 1) * 8 + 2 * ks + hi) ^ (drow & 15);
        bf16x8 va = *(const bf16x8*)(Vsb + drow * 256 + gr * 16);
        o[dblk] = __builtin_amdgcn_mfma_f32_32x32x16_bf16(va, pb[ks], o[dblk], 0, 0, 0);
      }
    }
    __builtin_amdgcn_s_setprio(0);

    __syncthreads();
    buf ^= 1;
  }

  // ---- epilogue: reduce l once, write Y ----
  {
    float l = (lacc[0] + lacc[1]) + (lacc[2] + lacc[3]);
    l += __shfl_xor(l, 32);
    float invl = 1.f / l;
    u16* Yrow = Y + ((long)b * NT + qi) * NC + h * HD;
#pragma unroll
    for (int dblk = 0; dblk < 4; ++dblk)
#pragma unroll
      for (int uu = 0; uu < 4; ++uu) {
        int d = dblk * 32 + 8 * uu + 4 * hi;
        int r0 = 4 * uu;
        *(uint2*)(Yrow + d) = make_uint2(
            packbf2(o[dblk][r0] * invl, o[dblk][r0 + 1] * invl),
            packbf2(o[dblk][r0 + 2] * invl, o[dblk][r0 + 3] * invl));
      }
  }
}

extern "C" void kernel_launch(void* const* d_in, const int* in_sizes, int n_in,
                              void* d_out, int out_size, void* d_ws, size_t ws_size,
                              hipStream_t stream) {
  const float* x = (const float*)d_in[0];
  const float* amask = (const float*)d_in[1];
  const float* w_qkv = (const float*)d_in[2];
  const float* w_proj = (const float*)d_in[3];

  const long MT = (long)NB * NT;  // 4096
  char* ws = (char*)d_ws;
  size_t off = 0;
  auto carve = [&](size_t bytes) -> char* {
    char* p = ws + off;
    off += (bytes + 255) & ~(size_t)255;
    return p;
  };
  u16* xb   = (u16*)carve((size_t)MT * NC * 2);       // A for gemm1; later Q
  u16* wqb  = (u16*)carve((size_t)NQKV * NC * 2);     // B for gemm1; later K + Vt
  u16* wpb  = (u16*)carve((size_t)NC * NC * 2);       // B for gemm2
  u16* qkvb = (u16*)carve((size_t)MT * NQKV * 2);     // C of gemm1; later Y
  float* tab = (float*)carve((size_t)NT * 128 * 4);

  u16* Qb = xb;
  u16* Kb = wqb;
  u16* Vtb = wqb + (size_t)NB * NKV * NT * HD;
  u16* Yb = qkvb;

  cvt3_kernel<<<dim3(2048), dim3(256), 0, stream>>>(
      x, xb, (int)(MT * NC / 4),
      w_qkv, wqb, (int)((long)NQKV * NC / 4),
      w_proj, wpb, (int)((long)NC * NC / 4));
  rope_tab_kernel<<<dim3(NT * 64 / 256), dim3(256), 0, stream>>>(tab);
  gemm256_kernel<1, 6><<<dim3(NQKV / 192, MT / 256), dim3(512), 0, stream>>>(xb, wqb, qkvb, (int)MT, NQKV, NC);
  rope_apply_kernel<<<dim3(NB * NT * 20 * 64 / 256), dim3(256), 0, stream>>>(qkvb, tab, Qb, Kb);
  vtrans_kernel<<<dim3(NT / 64 * 2, NB * NKV), dim3(256), 0, stream>>>(qkvb, Vtb);
  attn_kernel<<<dim3(512), dim3(256), 0, stream>>>(Qb, Kb, Vtb, amask, Yb);
  gemm256_kernel<0, 4><<<dim3(NC / 128, MT / 256), dim3(512), 0, stream>>>(Yb, wpb, d_out, (int)MT, NC, NC);
}